// Round 15
// baseline (337.275 us; speedup 1.0000x reference)
//
#include <hip/hip_runtime.h>
#include <hip/hip_bf16.h>
#include <stdint.h>

typedef __bf16 bf16x8 __attribute__((ext_vector_type(8)));
typedef float f32x4 __attribute__((ext_vector_type(4)));
typedef __hip_bfloat16 bf16;

__device__ __forceinline__ void gload16(const void* g, void* l) {
    __builtin_amdgcn_global_load_lds(
        (const __attribute__((address_space(1))) uint32_t*)g,
        (__attribute__((address_space(3))) uint32_t*)l,
        16, 0, 0);
}

// ---------------- elementwise convert fp32 -> bf16 (x) ----------------
__global__ void k_cvt_bf16(const float* __restrict__ in, bf16* __restrict__ out, int n4) {
    int i = blockIdx.x * blockDim.x + threadIdx.x;
    if (i >= n4) return;
    float4 v = reinterpret_cast<const float4*>(in)[i];
    union { bf16 h[4]; uint2 u; } pk;
    pk.h[0] = __float2bfloat16(v.x);
    pk.h[1] = __float2bfloat16(v.y);
    pk.h[2] = __float2bfloat16(v.z);
    pk.h[3] = __float2bfloat16(v.w);
    reinterpret_cast<uint2*>(out)[i] = pk.u;
}

// ---------------- rope cos/sin table [T][128] (cos j | sin j) ----------------
__global__ void k_rope_tbl(float* __restrict__ tbl) {
    int i = blockIdx.x * blockDim.x + threadIdx.x; // T*64
    int t = i >> 6, j = i & 63;
    float inv = powf(10000.0f, -(float)j * (1.0f / 64.0f));
    float f = (float)t * inv;
    tbl[t * 128 + j] = cosf(f);
    tbl[t * 128 + 64 + j] = sinf(f);
}

// ---------------- weight transpose + convert: W[k][n] fp32 -> Wt[n][k] bf16 ----------------
__global__ void k_wtrans(const float* __restrict__ w0, const float* __restrict__ w1,
                         const float* __restrict__ w2, const float* __restrict__ w3,
                         const float* __restrict__ w4, bf16* __restrict__ out) {
    __shared__ float tile[64][65];
    const float* srcs[5] = {w0, w1, w2, w3, w4};
    const float* src = srcs[blockIdx.z];
    bf16* dst = out + (size_t)blockIdx.z * 2048 * 2048;
    int k0 = blockIdx.x * 64, n0 = blockIdx.y * 64;
    int tx = threadIdx.x, ty = threadIdx.y; // 64 x 4
#pragma unroll
    for (int i = 0; i < 16; i++)
        tile[ty + 4 * i][tx] = src[(size_t)(k0 + ty + 4 * i) * 2048 + n0 + tx];
    __syncthreads();
#pragma unroll
    for (int i = 0; i < 16; i++)
        dst[(size_t)(n0 + ty + 4 * i) * 2048 + k0 + tx] = __float2bfloat16(tile[tx][ty + 4 * i]);
}

// ---------------- GEMM 128x128 (m97-structure), used for the output projection ----------------
__global__ __launch_bounds__(256) void k_gemm(
    const bf16* __restrict__ A, const bf16* __restrict__ Bt, float* __restrict__ C,
    int M, int N, int K) {
    __shared__ __align__(16) bf16 As[128 * 64];
    __shared__ __align__(16) bf16 Bs[128 * 64];
    int lane = threadIdx.x & 63, wave = threadIdx.x >> 6;
    int g = lane >> 4, cc = lane & 15;
    int wr = wave >> 1, wc = wave & 1;
    size_t m0 = (size_t)blockIdx.x * 128, n0 = (size_t)blockIdx.y * 128;
    const bf16* Ab = A + m0 * K;
    const bf16* Bb = Bt + (size_t)blockIdx.z * N * K + n0 * K;
    float* Cb = C + (size_t)blockIdx.z * M * N + m0 * N + n0;

    f32x4 acc[4][4];
#pragma unroll
    for (int i = 0; i < 4; i++)
#pragma unroll
        for (int j = 0; j < 4; j++) acc[i][j] = {0.f, 0.f, 0.f, 0.f};

    int scol = (lane & 7) * 8;
    for (int k0 = 0; k0 < K; k0 += 64) {
#pragma unroll
        for (int i = 0; i < 4; i++) {
            int ch = wave * 4 + i;
            int row = ch * 8 + (lane >> 3);
            gload16(&Ab[(size_t)row * K + k0 + scol], &As[ch * 512]);
            gload16(&Bb[(size_t)row * K + k0 + scol], &Bs[ch * 512]);
        }
        __syncthreads();
#pragma unroll
        for (int kk = 0; kk < 2; kk++) {
            bf16x8 af[4], bfr[4];
#pragma unroll
            for (int m = 0; m < 4; m++)
                af[m] = *reinterpret_cast<const bf16x8*>(&As[(wr * 64 + m * 16 + cc) * 64 + kk * 32 + g * 8]);
#pragma unroll
            for (int n = 0; n < 4; n++)
                bfr[n] = *reinterpret_cast<const bf16x8*>(&Bs[(wc * 64 + n * 16 + cc) * 64 + kk * 32 + g * 8]);
#pragma unroll
            for (int m = 0; m < 4; m++)
#pragma unroll
                for (int n = 0; n < 4; n++)
                    acc[m][n] = __builtin_amdgcn_mfma_f32_16x16x32_bf16(af[m], bfr[n], acc[m][n], 0, 0, 0);
        }
        __syncthreads();
    }
#pragma unroll
    for (int m = 0; m < 4; m++)
#pragma unroll
        for (int n = 0; n < 4; n++)
#pragma unroll
            for (int r = 0; r < 4; r++) {
                size_t row = wr * 64 + m * 16 + g * 4 + r;
                Cb[row * N + (wc * 64 + n * 16 + cc)] = acc[m][n][r];
            }
}

// ---------------- GEMM 256x256 v3: SINGLE-buffer region schedule, 64KB LDS ----------------
// Key change vs v2: one LDS buffer (64KB -> 2 resident blocks/CU; v2's 128KB capped at 1,
// which is why MfmaUtil stuck at 41% -- no co-resident block to cover barrier stalls).
// Regions die early (reads are reg-copies consumed in-phase): q0,q2@ph1; q4..q7@ph2;
// q1,q3@ph3. Stage tile t+1 into same buffer after each death barrier:
//   ph2 -> q0,q2 ; ph3 -> q4,q5 ; ph4 -> q6,q7,q1,q3.
// vmcnt(2)@ph2-end retires prev-ph4's q1,q3 (ready for ph3's READ_A(1));
// vmcnt(2)@ph4-end retires ph2+ph3+q6,q7 (ready for next ph1's reads); tail uses vmcnt(0).
__global__ __launch_bounds__(512, 2) void k_gemm256(
    const bf16* __restrict__ A, const bf16* __restrict__ Bt, bf16* __restrict__ C,
    int M, int N, int K) {
    __shared__ __align__(16) bf16 lds[8][64 * 64];
    const int tid = threadIdx.x;
    const int lane = tid & 63, wave = tid >> 6;
    const int g = lane >> 4, c = lane & 15, cx = c & 7;
    const int wr = wave >> 2, wc = wave & 3;  // 2M x 4N
    const int id = blockIdx.x;
    const int swz = (id & 7) * 64 + (id >> 3);
    const int xt = swz & 15, yt = (swz >> 4) & 7, zt = swz >> 7;
    const size_t m0 = (size_t)xt * 256, n0 = (size_t)yt * 256;
    const bf16* Ab = A + m0 * K;
    const bf16* Bb = Bt + (size_t)zt * (size_t)N * K + n0 * K;
    bf16* Cb = C + (size_t)zt * (size_t)M * N + m0 * N + n0;
    const int nt = K >> 6;

    const int srow = tid >> 3;
    const int scol = ((tid & 7) ^ (srow & 7)) * 8;

    auto stage = [&](int u, int q) {
        if (u >= nt) return;
        const bf16* src = (q < 4) ? &Ab[(size_t)(q * 64 + srow) * K]
                                  : &Bb[(size_t)((q - 4) * 64 + srow) * K];
        gload16(&src[((size_t)u << 6) + scol], &lds[q][wave * 512]);
    };

    f32x4 acc[8][4];
#pragma unroll
    for (int i = 0; i < 8; i++)
#pragma unroll
        for (int j = 0; j < 4; j++) acc[i][j] = {0.f, 0.f, 0.f, 0.f};

#pragma unroll
    for (int q = 0; q < 8; q++) stage(0, q);
    asm volatile("s_waitcnt vmcnt(0)" ::: "memory");
    __builtin_amdgcn_s_barrier();

    bf16x8 afr[4][2], bfr[2][2][2];

#define READ_A(mh)                                                                   \
    do {                                                                             \
        const bf16* aq = &lds[wr * 2 + (mh)][0];                                     \
        _Pragma("unroll") for (int m_ = 0; m_ < 4; m_++)                             \
            _Pragma("unroll") for (int kh = 0; kh < 2; kh++)                         \
                afr[m_][kh] = *reinterpret_cast<const bf16x8*>(                      \
                    aq + (m_ * 16 + c) * 64 + ((kh * 4 + g) ^ cx) * 8);              \
    } while (0)
#define READ_B(nh)                                                                   \
    do {                                                                             \
        const bf16* bq = &lds[4 + wc][0];                                            \
        _Pragma("unroll") for (int n_ = 0; n_ < 2; n_++)                             \
            _Pragma("unroll") for (int kh = 0; kh < 2; kh++)                         \
                bfr[nh][n_][kh] = *reinterpret_cast<const bf16x8*>(                  \
                    bq + (((nh)*2 + n_) * 16 + c) * 64 + ((kh * 4 + g) ^ cx) * 8);   \
    } while (0)
#define QUAD(mh, nh)                                                                 \
    do {                                                                             \
        __builtin_amdgcn_s_setprio(1);                                               \
        _Pragma("unroll") for (int kh = 0; kh < 2; kh++)                             \
            _Pragma("unroll") for (int m_ = 0; m_ < 4; m_++)                         \
                _Pragma("unroll") for (int n_ = 0; n_ < 2; n_++)                     \
                    acc[(mh)*4 + m_][(nh)*2 + n_] =                                  \
                        __builtin_amdgcn_mfma_f32_16x16x32_bf16(                     \
                            afr[m_][kh], bfr[nh][n_][kh],                            \
                            acc[(mh)*4 + m_][(nh)*2 + n_], 0, 0, 0);                 \
        __builtin_amdgcn_s_setprio(0);                                               \
    } while (0)

    for (int t = 0; t < nt; ++t) {
        // ---- ph1: read A0 + B0 (regions q0/q2 and rows 0..31 of 4+wc) ----
        READ_A(0);
        READ_B(0);
        __builtin_amdgcn_s_barrier();
        QUAD(0, 0);
        __builtin_amdgcn_s_barrier();
        // ---- ph2: read B1; stage t+1 into q0,q2 (died ph1) ----
        READ_B(1);
        stage(t + 1, 0); stage(t + 1, 2);
        if (t < nt - 1) asm volatile("s_waitcnt vmcnt(2)" ::: "memory");
        else            asm volatile("s_waitcnt vmcnt(0)" ::: "memory");
        __builtin_amdgcn_s_barrier();
        QUAD(0, 1);
        __builtin_amdgcn_s_barrier();
        // ---- ph3: read A1 (q1,q3: staged prev-ph4, retired by ph2's vmcnt); stage q4,q5 ----
        READ_A(1);
        stage(t + 1, 4); stage(t + 1, 5);
        __builtin_amdgcn_s_barrier();
        QUAD(1, 0);
        __builtin_amdgcn_s_barrier();
        // ---- ph4: stage q6,q7 then q1,q3 (A1 died ph3); retire all but q1,q3 ----
        stage(t + 1, 6); stage(t + 1, 7);
        stage(t + 1, 1); stage(t + 1, 3);
        if (t < nt - 1) asm volatile("s_waitcnt vmcnt(2)" ::: "memory");
        else            asm volatile("s_waitcnt vmcnt(0)" ::: "memory");
        __builtin_amdgcn_s_barrier();
        QUAD(1, 1);
        __builtin_amdgcn_s_barrier();
    }
#undef READ_A
#undef READ_B
#undef QUAD
#pragma unroll
    for (int m_ = 0; m_ < 8; m_++)
#pragma unroll
        for (int n_ = 0; n_ < 4; n_++)
#pragma unroll
            for (int r_ = 0; r_ < 4; r_++) {
                size_t row = wr * 128 + m_ * 16 + g * 4 + r_;
                Cb[row * N + wc * 64 + n_ * 16 + c] = __float2bfloat16(acc[m_][n_][r_]);
            }
}

// ---------------- RoPE + per-head RMS norm (q and k in one launch via blockIdx.y) ----------------
__global__ void k_rope_rms(const bf16* __restrict__ src_q, const bf16* __restrict__ src_k,
                           const float* __restrict__ qw, const float* __restrict__ kw,
                           const float* __restrict__ tbl, bf16* __restrict__ dst_q,
                           bf16* __restrict__ dst_k) {
    const int T = 2048;
    int role = blockIdx.y;
    const bf16* src = role ? src_k : src_q;
    const float* rmsw = role ? kw : qw;
    bf16* dst = role ? dst_k : dst_q;
    float outscale = role ? 1.0f : 0.08838834764831845f;
    int wv = blockIdx.x * 4 + (threadIdx.x >> 6); // over B*T*H, h fastest
    int lane = threadIdx.x & 63;
    int h = wv & 15, bt = wv >> 4;
    int t = bt & (T - 1), b_ = bt >> 11;
    const bf16* p = src + (size_t)bt * 2048 + h * 128;
    float a = __bfloat162float(p[lane]), b = __bfloat162float(p[lane + 64]);
    float cs = tbl[t * 128 + lane], sn = tbl[t * 128 + 64 + lane];
    float r1 = a * cs - b * sn, r2 = a * sn + b * cs;
    float ss = r1 * r1 + r2 * r2;
#pragma unroll
    for (int d = 1; d < 64; d <<= 1) ss += __shfl_xor(ss, d, 64);
    float rs = rsqrtf(ss * (1.0f / 128.0f) + 1e-5f);
    size_t o = ((size_t)(b_ * 16 + h) * T + t) * 128;
    dst[o + lane] = __float2bfloat16(r1 * rs * rmsw[lane] * outscale);
    dst[o + lane + 64] = __float2bfloat16(r2 * rs * rmsw[lane + 64] * outscale);
}

// ---------------- V transpose: bf16 [B*T][2048] -> bf16 Vt [BH][128][T] ----------------
__global__ void k_vtrans(const bf16* __restrict__ V, bf16* __restrict__ Vt) {
    const int T = 2048;
    __shared__ float tile[32][33];
    int bh = blockIdx.z, b_ = bh >> 4, h = bh & 15;
    int t0 = blockIdx.x * 32, d0 = blockIdx.y * 32;
    int tx = threadIdx.x, ty = threadIdx.y; // 32 x 8
#pragma unroll
    for (int i = 0; i < 4; i++)
        tile[ty + 8 * i][tx] =
            __bfloat162float(V[((size_t)(b_ * T + t0 + ty + 8 * i)) * 2048 + h * 128 + d0 + tx]);
    __syncthreads();
#pragma unroll
    for (int i = 0; i < 4; i++)
        Vt[((size_t)bh * 128 + d0 + ty + 8 * i) * T + t0 + tx] = __float2bfloat16(tile[tx][ty + 8 * i]);
}

// ---------------- causal flash attention v6: QBLK=64, permuted-K, in-reg P ----------------
__global__ __launch_bounds__(256) void k_attn(
    const bf16* __restrict__ Q, const bf16* __restrict__ K,
    const bf16* __restrict__ Vt, const bf16* __restrict__ gate,
    const float* __restrict__ ow, bf16* __restrict__ out) {
    const int T = 2048;
    __shared__ __align__(16) bf16 KsB[2][64 * 128];
    __shared__ __align__(16) bf16 VsB[2][128 * 64];
    int lane = threadIdx.x & 63, wave = threadIdx.x >> 6;
    int g = lane >> 4, c = lane & 15;
    int wg = blockIdx.x;
    int bh = wg & 31;          // XCD = wg%8 = bh%8 -> 4 heads per XCD (K+V = 4MB = one L2)
    int qt = 31 - (wg >> 5);   // heavy q-tiles launch first
    int q0 = qt * 64;
    const bf16* Qb = Q + (size_t)bh * T * 128;
    const bf16* Kb = K + (size_t)bh * T * 128;
    const bf16* Vb = Vt + (size_t)bh * 128 * T;

    int qrow = q0 + wave * 16 + c;
    bf16x8 qf[4];
#pragma unroll
    for (int kk = 0; kk < 4; kk++)
        qf[kk] = *reinterpret_cast<const bf16x8*>(&Qb[(size_t)qrow * 128 + kk * 32 + g * 8]);

    // staging constants: 4 waves x 4 chunks each for K and V; K rows permuted
    int kprow[4], klu[4], vrow[4], vlu[4];
#pragma unroll
    for (int i = 0; i < 4; i++) {
        int ch = wave * 4 + i;
        int p = ch * 4 + (lane >> 4);                       // staged K row position 0..63
        kprow[i] = ((p >> 5) & 1) * 32 + ((p >> 2) & 3) * 8 + ((p >> 4) & 1) * 4 + (p & 3);
        klu[i] = (lane & 15) ^ (p & 7);
        vrow[i] = ch * 8 + (lane >> 3);                     // V d-row 0..127 (linear)
        vlu[i] = (lane & 7) ^ (vrow[i] & 7);
    }
    auto stage = [&](int kv0, int b) {
#pragma unroll
        for (int i = 0; i < 4; i++) {
            int ch = wave * 4 + i;
            gload16(&Kb[(size_t)(kv0 + kprow[i]) * 128 + klu[i] * 8], &KsB[b][ch * 512]);
            gload16(&Vb[(size_t)vrow[i] * T + kv0 + vlu[i] * 8], &VsB[b][ch * 512]);
        }
    };

    f32x4 acc[8];
#pragma unroll
    for (int i = 0; i < 8; i++) acc[i] = {0.f, 0.f, 0.f, 0.f};
    float m = -INFINITY, l = 0.f;

    int ntiles = qt + 1;
    stage(0, 0);
    __syncthreads();
    int cur = 0;
    for (int it = 0; it < ntiles; ++it) {
        int kv0 = it * 64;
        if (it + 1 < ntiles) stage(kv0 + 64, cur ^ 1);
        const bf16* Ks = KsB[cur];
        const bf16* Vs = VsB[cur];

        f32x4 s[4];
#pragma unroll
        for (int nf = 0; nf < 4; nf++) s[nf] = {0.f, 0.f, 0.f, 0.f};
#pragma unroll
        for (int nf = 0; nf < 4; nf++)
#pragma unroll
            for (int kk = 0; kk < 4; kk++) {
                int pu = (kk * 4 + g) ^ (c & 7);
                bf16x8 kf = *reinterpret_cast<const bf16x8*>(&Ks[(nf * 16 + c) * 128 + pu * 8]);
                s[nf] = __builtin_amdgcn_mfma_f32_16x16x32_bf16(kf, qf[kk], s[nf], 0, 0, 0);
            }
        // causal mask on the permuted true kv: kv_true = kv0 + 32*(nf>>1) + 8g + 4*(nf&1) + r
        if (it == ntiles - 1) {
#pragma unroll
            for (int nf = 0; nf < 4; nf++)
#pragma unroll
                for (int r = 0; r < 4; r++)
                    if (kv0 + (nf >> 1) * 32 + g * 8 + (nf & 1) * 4 + r > qrow)
                        s[nf][r] = -1e30f;
        }
        float mx = -INFINITY;
#pragma unroll
        for (int nf = 0; nf < 4; nf++)
#pragma unroll
            for (int r = 0; r < 4; r++) mx = fmaxf(mx, s[nf][r]);
        mx = fmaxf(mx, __shfl_xor(mx, 16, 64));
        mx = fmaxf(mx, __shfl_xor(mx, 32, 64));
        if (__all(mx - m <= 8.0f)) {  // T13 defer-max
            float rsum = 0.f;
#pragma unroll
            for (int nf = 0; nf < 4; nf++)
#pragma unroll
                for (int r = 0; r < 4; r++) {
                    float p = __expf(s[nf][r] - m);
                    s[nf][r] = p;
                    rsum += p;
                }
            rsum += __shfl_xor(rsum, 16, 64);
            rsum += __shfl_xor(rsum, 32, 64);
            l += rsum;
        } else {
            float mnew = fmaxf(m, mx);
            float alpha = __expf(m - mnew);
            m = mnew;
            float rsum = 0.f;
#pragma unroll
            for (int nf = 0; nf < 4; nf++)
#pragma unroll
                for (int r = 0; r < 4; r++) {
                    float p = __expf(s[nf][r] - mnew);
                    s[nf][r] = p;
                    rsum += p;
                }
            rsum += __shfl_xor(rsum, 16, 64);
            rsum += __shfl_xor(rsum, 32, 64);
            l = l * alpha + rsum;
            float al[4];
#pragma unroll
            for (int r = 0; r < 4; r++) al[r] = __shfl(alpha, g * 4 + r, 64);
#pragma unroll
            for (int nf = 0; nf < 8; nf++)
#pragma unroll
                for (int r = 0; r < 4; r++) acc[nf][r] *= al[r];
        }
        // PV: A-frag fully in-register (permuted-K QK^T layout)
#pragma unroll
        for (int kk2 = 0; kk2 < 2; kk2++) {
            union { bf16 h[8]; bf16x8 v; } pf;
#pragma unroll
            for (int r = 0; r < 4; r++) {
                pf.h[r] = __float2bfloat16(s[2 * kk2][r]);
                pf.h[4 + r] = __float2bfloat16(s[2 * kk2 + 1][r]);
            }
#pragma unroll
            for (int nf = 0; nf < 8; nf++) {
                int pu = (kk2 * 4 + g) ^ (c & 7);
                bf16x8 vf = *reinterpret_cast<const bf16x8*>(&Vs[(nf * 16 + c) * 64 + pu * 8]);
                acc[nf] = __builtin_amdgcn_mfma_f32_16x16x32_bf16(pf.v, vf, acc[nf], 0, 0, 0);
            }
        }
        __syncthreads();
        cur ^= 1;
    }
    // ---- fused epilogue: 1/l, o-norm, silu(gate) ----
    float inv = 1.0f / l;
    float iv[4];
#pragma unroll
    for (int r = 0; r < 4; r++) iv[r] = __shfl(inv, g * 4 + r, 64);
    int b_ = bh >> 4, h = bh & 15;
    float owv[8];
#pragma unroll
    for (int nf = 0; nf < 8; nf++) owv[nf] = ow[nf * 16 + c];
#pragma unroll
    for (int r = 0; r < 4; r++) {
        int row = q0 + wave * 16 + g * 4 + r;
        float y[8];
        float ss = 0.f;
#pragma unroll
        for (int nf = 0; nf < 8; nf++) {
            y[nf] = acc[nf][r] * iv[r];
            ss += y[nf] * y[nf];
        }
        ss += __shfl_xor(ss, 1, 64);
        ss += __shfl_xor(ss, 2, 64);
        ss += __shfl_xor(ss, 4, 64);
        ss += __shfl_xor(ss, 8, 64);
        float rs = rsqrtf(ss * (1.0f / 128.0f) + 1e-5f);
        size_t gi = ((size_t)(b_ * T + row)) * 2048 + h * 128;
#pragma unroll
        for (int nf = 0; nf < 8; nf++) {
            int col = nf * 16 + c;
            float gv = __bfloat162float(gate[gi + col]);
            gv = gv / (1.f + __expf(-gv));
            out[gi + col] = __float2bfloat16(y[nf] * rs * owv[nf] * gv);
        }
    }
}

extern "C" void kernel_launch(void* const* d_in, const int* in_sizes, int n_in,
                              void* d_out, int out_size, void* d_ws, size_t ws_size,
                              hipStream_t stream) {
    const float* x  = (const float*)d_in[0];
    const float* Wq = (const float*)d_in[1];
    const float* Wk = (const float*)d_in[2];
    const float* Wv = (const float*)d_in[3];
    const float* Wg = (const float*)d_in[4];
    const float* Wo = (const float*)d_in[5];
    const float* qw = (const float*)d_in[6];
    const float* kw = (const float*)d_in[7];
    const float* ow = (const float*)d_in[8];

    const size_t M = 4096, HID = 2048;
    char* w = (char*)d_ws;
    bf16*  xb    = (bf16*)(w);                     // @0          16,777,216 B
    bf16*  Wt    = (bf16*)(w + 16777216);          // @16M        41,943,040 B [5][2048][2048]
    bf16*  qkvg  = (bf16*)(w + 58720256);          // @56M        67,108,864 B [4][4096][2048] bf16
    bf16*  q_att = (bf16*)(w + 125829120);         //             16,777,216 B [32][2048][128]
    bf16*  k_att = (bf16*)(w + 142606336);         //             16,777,216 B
    bf16*  vt    = (bf16*)(w + 159383552);         //             16,777,216 B [32][128][2048]
    float* tbl   = (float*)(w + 176160768);        //              1,048,576 B [2048][128]
    bf16*  yg    = (bf16*)(w + 177209344);         //             16,777,216 B [B*T][2048]

    k_cvt_bf16<<<8192, 256, 0, stream>>>(x, xb, (int)(M * HID / 4));
    k_rope_tbl<<<512, 256, 0, stream>>>(tbl);
    k_wtrans<<<dim3(32, 32, 5), dim3(64, 4), 0, stream>>>(Wq, Wk, Wv, Wg, Wo, Wt);
    // fused Q/K/V/Gate projection (v3: single-buffer 64KB LDS -> 2 blocks/CU)
    k_gemm256<<<512, 512, 0, stream>>>(xb, Wt, qkvg, (int)M, 2048, 2048);
    // rope + rms for q and k in one launch (+ fold 1/sqrt(D) into q)
    k_rope_rms<<<dim3(16384, 2), 256, 0, stream>>>(qkvg, qkvg + M * HID, qw, kw, tbl,
                                                   q_att, k_att);
    k_vtrans<<<dim3(64, 4, 32), dim3(32, 8), 0, stream>>>(qkvg + 2 * M * HID, vt);
    // attention (QBLK=64, permuted-K, in-register P) with fused o-norm + silu(gate) -> yg
    k_attn<<<1024, 256, 0, stream>>>(q_att, k_att, vt, qkvg + 3 * M * HID, ow, yg);
    // output projection (m97 128^2, fp32 out)
    k_gemm<<<dim3(32, 16, 1), 256, 0, stream>>>(yg, Wt + (size_t)4 * 2048 * 2048, (float*)d_out,
                                                (int)M, 2048, 2048);
}

// Round 16
// 314.461 us; speedup vs baseline: 1.0726x; 1.0726x over previous
//
#include <hip/hip_runtime.h>
#include <hip/hip_bf16.h>
#include <stdint.h>

typedef __bf16 bf16x8 __attribute__((ext_vector_type(8)));
typedef float f32x4 __attribute__((ext_vector_type(4)));
typedef __hip_bfloat16 bf16;

__device__ __forceinline__ void gload16(const void* g, void* l) {
    __builtin_amdgcn_global_load_lds(
        (const __attribute__((address_space(1))) uint32_t*)g,
        (__attribute__((address_space(3))) uint32_t*)l,
        16, 0, 0);
}

// ---------------- elementwise convert fp32 -> bf16 (x) ----------------
__global__ void k_cvt_bf16(const float* __restrict__ in, bf16* __restrict__ out, int n4) {
    int i = blockIdx.x * blockDim.x + threadIdx.x;
    if (i >= n4) return;
    float4 v = reinterpret_cast<const float4*>(in)[i];
    union { bf16 h[4]; uint2 u; } pk;
    pk.h[0] = __float2bfloat16(v.x);
    pk.h[1] = __float2bfloat16(v.y);
    pk.h[2] = __float2bfloat16(v.z);
    pk.h[3] = __float2bfloat16(v.w);
    reinterpret_cast<uint2*>(out)[i] = pk.u;
}

// ---------------- rope cos/sin table [T][128] (cos j | sin j) ----------------
__global__ void k_rope_tbl(float* __restrict__ tbl) {
    int i = blockIdx.x * blockDim.x + threadIdx.x; // T*64
    int t = i >> 6, j = i & 63;
    float inv = powf(10000.0f, -(float)j * (1.0f / 64.0f));
    float f = (float)t * inv;
    tbl[t * 128 + j] = cosf(f);
    tbl[t * 128 + 64 + j] = sinf(f);
}

// ---------------- weight transpose + convert: W[k][n] fp32 -> Wt[n][k] bf16 ----------------
__global__ void k_wtrans(const float* __restrict__ w0, const float* __restrict__ w1,
                         const float* __restrict__ w2, const float* __restrict__ w3,
                         const float* __restrict__ w4, bf16* __restrict__ out) {
    __shared__ float tile[64][65];
    const float* srcs[5] = {w0, w1, w2, w3, w4};
    const float* src = srcs[blockIdx.z];
    bf16* dst = out + (size_t)blockIdx.z * 2048 * 2048;
    int k0 = blockIdx.x * 64, n0 = blockIdx.y * 64;
    int tx = threadIdx.x, ty = threadIdx.y; // 64 x 4
#pragma unroll
    for (int i = 0; i < 16; i++)
        tile[ty + 4 * i][tx] = src[(size_t)(k0 + ty + 4 * i) * 2048 + n0 + tx];
    __syncthreads();
#pragma unroll
    for (int i = 0; i < 16; i++)
        dst[(size_t)(n0 + ty + 4 * i) * 2048 + k0 + tx] = __float2bfloat16(tile[tx][ty + 4 * i]);
}

// ---------------- GEMM 128x128 (m97-structure), used for the output projection ----------------
__global__ __launch_bounds__(256) void k_gemm(
    const bf16* __restrict__ A, const bf16* __restrict__ Bt, float* __restrict__ C,
    int M, int N, int K) {
    __shared__ __align__(16) bf16 As[128 * 64];
    __shared__ __align__(16) bf16 Bs[128 * 64];
    int lane = threadIdx.x & 63, wave = threadIdx.x >> 6;
    int g = lane >> 4, cc = lane & 15;
    int wr = wave >> 1, wc = wave & 1;
    size_t m0 = (size_t)blockIdx.x * 128, n0 = (size_t)blockIdx.y * 128;
    const bf16* Ab = A + m0 * K;
    const bf16* Bb = Bt + (size_t)blockIdx.z * N * K + n0 * K;
    float* Cb = C + (size_t)blockIdx.z * M * N + m0 * N + n0;

    f32x4 acc[4][4];
#pragma unroll
    for (int i = 0; i < 4; i++)
#pragma unroll
        for (int j = 0; j < 4; j++) acc[i][j] = {0.f, 0.f, 0.f, 0.f};

    int scol = (lane & 7) * 8;
    for (int k0 = 0; k0 < K; k0 += 64) {
#pragma unroll
        for (int i = 0; i < 4; i++) {
            int ch = wave * 4 + i;
            int row = ch * 8 + (lane >> 3);
            gload16(&Ab[(size_t)row * K + k0 + scol], &As[ch * 512]);
            gload16(&Bb[(size_t)row * K + k0 + scol], &Bs[ch * 512]);
        }
        __syncthreads();
#pragma unroll
        for (int kk = 0; kk < 2; kk++) {
            bf16x8 af[4], bfr[4];
#pragma unroll
            for (int m = 0; m < 4; m++)
                af[m] = *reinterpret_cast<const bf16x8*>(&As[(wr * 64 + m * 16 + cc) * 64 + kk * 32 + g * 8]);
#pragma unroll
            for (int n = 0; n < 4; n++)
                bfr[n] = *reinterpret_cast<const bf16x8*>(&Bs[(wc * 64 + n * 16 + cc) * 64 + kk * 32 + g * 8]);
#pragma unroll
            for (int m = 0; m < 4; m++)
#pragma unroll
                for (int n = 0; n < 4; n++)
                    acc[m][n] = __builtin_amdgcn_mfma_f32_16x16x32_bf16(af[m], bfr[n], acc[m][n], 0, 0, 0);
        }
        __syncthreads();
    }
#pragma unroll
    for (int m = 0; m < 4; m++)
#pragma unroll
        for (int n = 0; n < 4; n++)
#pragma unroll
            for (int r = 0; r < 4; r++) {
                size_t row = wr * 64 + m * 16 + g * 4 + r;
                Cb[row * N + (wc * 64 + n * 16 + cc)] = acc[m][n][r];
            }
}

// ---------------- GEMM 256x256 v2b (round-14 best): spread-read 4-phase, dbuf, bf16 out ----------------
__global__ __launch_bounds__(512, 2) void k_gemm256(
    const bf16* __restrict__ A, const bf16* __restrict__ Bt, bf16* __restrict__ C,
    int M, int N, int K) {
    __shared__ __align__(16) bf16 lds[2][8][64 * 64];
    const int tid = threadIdx.x;
    const int lane = tid & 63, wave = tid >> 6;
    const int g = lane >> 4, c = lane & 15, cx = c & 7;
    const int wr = wave >> 2, wc = wave & 3;  // 2M x 4N
    const int id = blockIdx.x;
    const int swz = (id & 7) * 64 + (id >> 3);
    const int xt = swz & 15, yt = (swz >> 4) & 7, zt = swz >> 7;
    const size_t m0 = (size_t)xt * 256, n0 = (size_t)yt * 256;
    const bf16* Ab = A + m0 * K;
    const bf16* Bb = Bt + (size_t)zt * (size_t)N * K + n0 * K;
    bf16* Cb = C + (size_t)zt * (size_t)M * N + m0 * N + n0;
    const int nt = K >> 6;

    const int srow = tid >> 3;
    const int scol = ((tid & 7) ^ (srow & 7)) * 8;

    auto stage = [&](int u, int q) {
        if (u >= nt) return;
        const bf16* src = (q < 4) ? &Ab[(size_t)(q * 64 + srow) * K]
                                  : &Bb[(size_t)((q - 4) * 64 + srow) * K];
        gload16(&src[((size_t)u << 6) + scol], &lds[u & 1][q][wave * 512]);
    };

    f32x4 acc[8][4];
#pragma unroll
    for (int i = 0; i < 8; i++)
#pragma unroll
        for (int j = 0; j < 4; j++) acc[i][j] = {0.f, 0.f, 0.f, 0.f};

#pragma unroll
    for (int q = 0; q < 8; q++) stage(0, q);
    stage(1, 0); stage(1, 2); stage(1, 4); stage(1, 5); stage(1, 6); stage(1, 7);
    asm volatile("s_waitcnt vmcnt(6)" ::: "memory");
    __builtin_amdgcn_s_barrier();

    bf16x8 afr[4][2], bfr[2][2][2];

#define READ_A(mh)                                                                   \
    do {                                                                             \
        const bf16* aq = &lds[t & 1][wr * 2 + (mh)][0];                              \
        _Pragma("unroll") for (int m_ = 0; m_ < 4; m_++)                             \
            _Pragma("unroll") for (int kh = 0; kh < 2; kh++)                         \
                afr[m_][kh] = *reinterpret_cast<const bf16x8*>(                      \
                    aq + (m_ * 16 + c) * 64 + ((kh * 4 + g) ^ cx) * 8);              \
    } while (0)
#define READ_B(nh)                                                                   \
    do {                                                                             \
        const bf16* bq = &lds[t & 1][4 + wc][0];                                     \
        _Pragma("unroll") for (int n_ = 0; n_ < 2; n_++)                             \
            _Pragma("unroll") for (int kh = 0; kh < 2; kh++)                         \
                bfr[nh][n_][kh] = *reinterpret_cast<const bf16x8*>(                  \
                    bq + (((nh)*2 + n_) * 16 + c) * 64 + ((kh * 4 + g) ^ cx) * 8);   \
    } while (0)
#define QUAD(mh, nh)                                                                 \
    do {                                                                             \
        __builtin_amdgcn_s_setprio(1);                                               \
        _Pragma("unroll") for (int kh = 0; kh < 2; kh++)                             \
            _Pragma("unroll") for (int m_ = 0; m_ < 4; m_++)                         \
                _Pragma("unroll") for (int n_ = 0; n_ < 2; n_++)                     \
                    acc[(mh)*4 + m_][(nh)*2 + n_] =                                  \
                        __builtin_amdgcn_mfma_f32_16x16x32_bf16(                     \
                            afr[m_][kh], bfr[nh][n_][kh],                            \
                            acc[(mh)*4 + m_][(nh)*2 + n_], 0, 0, 0);                 \
        __builtin_amdgcn_s_setprio(0);                                               \
    } while (0)

    for (int t = 0; t < nt; ++t) {
        // ---- ph1 ----
        READ_A(0);
        READ_B(0);
        stage(t + 1, 1); stage(t + 1, 3);
        __builtin_amdgcn_s_barrier();
        QUAD(0, 0);
        __builtin_amdgcn_s_barrier();
        // ---- ph2 ----
        READ_B(1);
        stage(t + 2, 0); stage(t + 2, 2);
        __builtin_amdgcn_s_barrier();
        QUAD(0, 1);
        __builtin_amdgcn_s_barrier();
        // ---- ph3 ----
        READ_A(1);
        stage(t + 2, 4); stage(t + 2, 5);
        __builtin_amdgcn_s_barrier();
        QUAD(1, 0);
        __builtin_amdgcn_s_barrier();
        // ---- ph4 ----
        stage(t + 2, 6); stage(t + 2, 7);
        if (t < nt - 2) asm volatile("s_waitcnt vmcnt(6)" ::: "memory");
        else            asm volatile("s_waitcnt vmcnt(0)" ::: "memory");
        __builtin_amdgcn_s_barrier();
        QUAD(1, 1);
        __builtin_amdgcn_s_barrier();
    }
#undef READ_A
#undef READ_B
#undef QUAD
#pragma unroll
    for (int m_ = 0; m_ < 8; m_++)
#pragma unroll
        for (int n_ = 0; n_ < 4; n_++)
#pragma unroll
            for (int r_ = 0; r_ < 4; r_++) {
                size_t row = wr * 128 + m_ * 16 + g * 4 + r_;
                Cb[row * N + wc * 64 + n_ * 16 + c] = __float2bfloat16(acc[m_][n_][r_]);
            }
}

// ---------------- RoPE + per-head RMS norm (q and k in one launch via blockIdx.y) ----------------
__global__ void k_rope_rms(const bf16* __restrict__ src_q, const bf16* __restrict__ src_k,
                           const float* __restrict__ qw, const float* __restrict__ kw,
                           const float* __restrict__ tbl, bf16* __restrict__ dst_q,
                           bf16* __restrict__ dst_k) {
    const int T = 2048;
    int role = blockIdx.y;
    const bf16* src = role ? src_k : src_q;
    const float* rmsw = role ? kw : qw;
    bf16* dst = role ? dst_k : dst_q;
    float outscale = role ? 1.0f : 0.08838834764831845f;
    int wv = blockIdx.x * 4 + (threadIdx.x >> 6); // over B*T*H, h fastest
    int lane = threadIdx.x & 63;
    int h = wv & 15, bt = wv >> 4;
    int t = bt & (T - 1), b_ = bt >> 11;
    const bf16* p = src + (size_t)bt * 2048 + h * 128;
    float a = __bfloat162float(p[lane]), b = __bfloat162float(p[lane + 64]);
    float cs = tbl[t * 128 + lane], sn = tbl[t * 128 + 64 + lane];
    float r1 = a * cs - b * sn, r2 = a * sn + b * cs;
    float ss = r1 * r1 + r2 * r2;
#pragma unroll
    for (int d = 1; d < 64; d <<= 1) ss += __shfl_xor(ss, d, 64);
    float rs = rsqrtf(ss * (1.0f / 128.0f) + 1e-5f);
    size_t o = ((size_t)(b_ * 16 + h) * T + t) * 128;
    dst[o + lane] = __float2bfloat16(r1 * rs * rmsw[lane] * outscale);
    dst[o + lane + 64] = __float2bfloat16(r2 * rs * rmsw[lane + 64] * outscale);
}

// ---------------- V transpose: bf16 [B*T][2048] -> bf16 Vt [BH][128][T] ----------------
__global__ void k_vtrans(const bf16* __restrict__ V, bf16* __restrict__ Vt) {
    const int T = 2048;
    __shared__ float tile[32][33];
    int bh = blockIdx.z, b_ = bh >> 4, h = bh & 15;
    int t0 = blockIdx.x * 32, d0 = blockIdx.y * 32;
    int tx = threadIdx.x, ty = threadIdx.y; // 32 x 8
#pragma unroll
    for (int i = 0; i < 4; i++)
        tile[ty + 8 * i][tx] =
            __bfloat162float(V[((size_t)(b_ * T + t0 + ty + 8 * i)) * 2048 + h * 128 + d0 + tx]);
    __syncthreads();
#pragma unroll
    for (int i = 0; i < 4; i++)
        Vt[((size_t)bh * 128 + d0 + ty + 8 * i) * T + t0 + tx] = __float2bfloat16(tile[tx][ty + 8 * i]);
}

// ---------------- causal flash attention v6: QBLK=64, permuted-K, in-reg P ----------------
__global__ __launch_bounds__(256) void k_attn(
    const bf16* __restrict__ Q, const bf16* __restrict__ K,
    const bf16* __restrict__ Vt, const bf16* __restrict__ gate,
    const float* __restrict__ ow, bf16* __restrict__ out) {
    const int T = 2048;
    __shared__ __align__(16) bf16 KsB[2][64 * 128];
    __shared__ __align__(16) bf16 VsB[2][128 * 64];
    int lane = threadIdx.x & 63, wave = threadIdx.x >> 6;
    int g = lane >> 4, c = lane & 15;
    int wg = blockIdx.x;
    int bh = wg & 31;          // XCD = wg%8 = bh%8 -> 4 heads per XCD (K+V = 4MB = one L2)
    int qt = 31 - (wg >> 5);   // heavy q-tiles launch first
    int q0 = qt * 64;
    const bf16* Qb = Q + (size_t)bh * T * 128;
    const bf16* Kb = K + (size_t)bh * T * 128;
    const bf16* Vb = Vt + (size_t)bh * 128 * T;

    int qrow = q0 + wave * 16 + c;
    bf16x8 qf[4];
#pragma unroll
    for (int kk = 0; kk < 4; kk++)
        qf[kk] = *reinterpret_cast<const bf16x8*>(&Qb[(size_t)qrow * 128 + kk * 32 + g * 8]);

    // staging constants: 4 waves x 4 chunks each for K and V; K rows permuted
    int kprow[4], klu[4], vrow[4], vlu[4];
#pragma unroll
    for (int i = 0; i < 4; i++) {
        int ch = wave * 4 + i;
        int p = ch * 4 + (lane >> 4);                       // staged K row position 0..63
        kprow[i] = ((p >> 5) & 1) * 32 + ((p >> 2) & 3) * 8 + ((p >> 4) & 1) * 4 + (p & 3);
        klu[i] = (lane & 15) ^ (p & 7);
        vrow[i] = ch * 8 + (lane >> 3);                     // V d-row 0..127 (linear)
        vlu[i] = (lane & 7) ^ (vrow[i] & 7);
    }
    auto stage = [&](int kv0, int b) {
#pragma unroll
        for (int i = 0; i < 4; i++) {
            int ch = wave * 4 + i;
            gload16(&Kb[(size_t)(kv0 + kprow[i]) * 128 + klu[i] * 8], &KsB[b][ch * 512]);
            gload16(&Vb[(size_t)vrow[i] * T + kv0 + vlu[i] * 8], &VsB[b][ch * 512]);
        }
    };

    f32x4 acc[8];
#pragma unroll
    for (int i = 0; i < 8; i++) acc[i] = {0.f, 0.f, 0.f, 0.f};
    float m = -INFINITY, l = 0.f;

    int ntiles = qt + 1;
    stage(0, 0);
    __syncthreads();
    int cur = 0;
    for (int it = 0; it < ntiles; ++it) {
        int kv0 = it * 64;
        if (it + 1 < ntiles) stage(kv0 + 64, cur ^ 1);
        const bf16* Ks = KsB[cur];
        const bf16* Vs = VsB[cur];

        f32x4 s[4];
#pragma unroll
        for (int nf = 0; nf < 4; nf++) s[nf] = {0.f, 0.f, 0.f, 0.f};
#pragma unroll
        for (int nf = 0; nf < 4; nf++)
#pragma unroll
            for (int kk = 0; kk < 4; kk++) {
                int pu = (kk * 4 + g) ^ (c & 7);
                bf16x8 kf = *reinterpret_cast<const bf16x8*>(&Ks[(nf * 16 + c) * 128 + pu * 8]);
                s[nf] = __builtin_amdgcn_mfma_f32_16x16x32_bf16(kf, qf[kk], s[nf], 0, 0, 0);
            }
        // causal mask on the permuted true kv: kv_true = kv0 + 32*(nf>>1) + 8g + 4*(nf&1) + r
        if (it == ntiles - 1) {
#pragma unroll
            for (int nf = 0; nf < 4; nf++)
#pragma unroll
                for (int r = 0; r < 4; r++)
                    if (kv0 + (nf >> 1) * 32 + g * 8 + (nf & 1) * 4 + r > qrow)
                        s[nf][r] = -1e30f;
        }
        float mx = -INFINITY;
#pragma unroll
        for (int nf = 0; nf < 4; nf++)
#pragma unroll
            for (int r = 0; r < 4; r++) mx = fmaxf(mx, s[nf][r]);
        mx = fmaxf(mx, __shfl_xor(mx, 16, 64));
        mx = fmaxf(mx, __shfl_xor(mx, 32, 64));
        if (__all(mx - m <= 8.0f)) {  // T13 defer-max
            float rsum = 0.f;
#pragma unroll
            for (int nf = 0; nf < 4; nf++)
#pragma unroll
                for (int r = 0; r < 4; r++) {
                    float p = __expf(s[nf][r] - m);
                    s[nf][r] = p;
                    rsum += p;
                }
            rsum += __shfl_xor(rsum, 16, 64);
            rsum += __shfl_xor(rsum, 32, 64);
            l += rsum;
        } else {
            float mnew = fmaxf(m, mx);
            float alpha = __expf(m - mnew);
            m = mnew;
            float rsum = 0.f;
#pragma unroll
            for (int nf = 0; nf < 4; nf++)
#pragma unroll
                for (int r = 0; r < 4; r++) {
                    float p = __expf(s[nf][r] - mnew);
                    s[nf][r] = p;
                    rsum += p;
                }
            rsum += __shfl_xor(rsum, 16, 64);
            rsum += __shfl_xor(rsum, 32, 64);
            l = l * alpha + rsum;
            float al[4];
#pragma unroll
            for (int r = 0; r < 4; r++) al[r] = __shfl(alpha, g * 4 + r, 64);
#pragma unroll
            for (int nf = 0; nf < 8; nf++)
#pragma unroll
                for (int r = 0; r < 4; r++) acc[nf][r] *= al[r];
        }
        // PV: A-frag fully in-register (permuted-K QK^T layout)
#pragma unroll
        for (int kk2 = 0; kk2 < 2; kk2++) {
            union { bf16 h[8]; bf16x8 v; } pf;
#pragma unroll
            for (int r = 0; r < 4; r++) {
                pf.h[r] = __float2bfloat16(s[2 * kk2][r]);
                pf.h[4 + r] = __float2bfloat16(s[2 * kk2 + 1][r]);
            }
#pragma unroll
            for (int nf = 0; nf < 8; nf++) {
                int pu = (kk2 * 4 + g) ^ (c & 7);
                bf16x8 vf = *reinterpret_cast<const bf16x8*>(&Vs[(nf * 16 + c) * 64 + pu * 8]);
                acc[nf] = __builtin_amdgcn_mfma_f32_16x16x32_bf16(pf.v, vf, acc[nf], 0, 0, 0);
            }
        }
        __syncthreads();
        cur ^= 1;
    }
    // ---- fused epilogue: 1/l, o-norm, silu(gate) ----
    float inv = 1.0f / l;
    float iv[4];
#pragma unroll
    for (int r = 0; r < 4; r++) iv[r] = __shfl(inv, g * 4 + r, 64);
    int b_ = bh >> 4, h = bh & 15;
    float owv[8];
#pragma unroll
    for (int nf = 0; nf < 8; nf++) owv[nf] = ow[nf * 16 + c];
#pragma unroll
    for (int r = 0; r < 4; r++) {
        int row = q0 + wave * 16 + g * 4 + r;
        float y[8];
        float ss = 0.f;
#pragma unroll
        for (int nf = 0; nf < 8; nf++) {
            y[nf] = acc[nf][r] * iv[r];
            ss += y[nf] * y[nf];
        }
        ss += __shfl_xor(ss, 1, 64);
        ss += __shfl_xor(ss, 2, 64);
        ss += __shfl_xor(ss, 4, 64);
        ss += __shfl_xor(ss, 8, 64);
        float rs = rsqrtf(ss * (1.0f / 128.0f) + 1e-5f);
        size_t gi = ((size_t)(b_ * T + row)) * 2048 + h * 128;
#pragma unroll
        for (int nf = 0; nf < 8; nf++) {
            int col = nf * 16 + c;
            float gv = __bfloat162float(gate[gi + col]);
            gv = gv / (1.f + __expf(-gv));
            out[gi + col] = __float2bfloat16(y[nf] * rs * owv[nf] * gv);
        }
    }
}

extern "C" void kernel_launch(void* const* d_in, const int* in_sizes, int n_in,
                              void* d_out, int out_size, void* d_ws, size_t ws_size,
                              hipStream_t stream) {
    const float* x  = (const float*)d_in[0];
    const float* Wq = (const float*)d_in[1];
    const float* Wk = (const float*)d_in[2];
    const float* Wv = (const float*)d_in[3];
    const float* Wg = (const float*)d_in[4];
    const float* Wo = (const float*)d_in[5];
    const float* qw = (const float*)d_in[6];
    const float* kw = (const float*)d_in[7];
    const float* ow = (const float*)d_in[8];

    const size_t M = 4096, HID = 2048;
    char* w = (char*)d_ws;
    bf16*  xb    = (bf16*)(w);                     // @0          16,777,216 B
    bf16*  Wt    = (bf16*)(w + 16777216);          // @16M        41,943,040 B [5][2048][2048]
    bf16*  qkvg  = (bf16*)(w + 58720256);          // @56M        67,108,864 B [4][4096][2048] bf16
    bf16*  q_att = (bf16*)(w + 125829120);         //             16,777,216 B [32][2048][128]
    bf16*  k_att = (bf16*)(w + 142606336);         //             16,777,216 B
    bf16*  vt    = (bf16*)(w + 159383552);         //             16,777,216 B [32][128][2048]
    float* tbl   = (float*)(w + 176160768);        //              1,048,576 B [2048][128]
    bf16*  yg    = (bf16*)(w + 177209344);         //             16,777,216 B [B*T][2048]

    k_cvt_bf16<<<8192, 256, 0, stream>>>(x, xb, (int)(M * HID / 4));
    k_rope_tbl<<<512, 256, 0, stream>>>(tbl);
    k_wtrans<<<dim3(32, 32, 5), dim3(64, 4), 0, stream>>>(Wq, Wk, Wv, Wg, Wo, Wt);
    // fused Q/K/V/Gate projection (v2b: best measured, 150us / 41% MfmaUtil)
    k_gemm256<<<512, 512, 0, stream>>>(xb, Wt, qkvg, (int)M, 2048, 2048);
    // rope + rms for q and k in one launch (+ fold 1/sqrt(D) into q)
    k_rope_rms<<<dim3(16384, 2), 256, 0, stream>>>(qkvg, qkvg + M * HID, qw, kw, tbl,
                                                   q_att, k_att);
    k_vtrans<<<dim3(64, 4, 32), dim3(32, 8), 0, stream>>>(qkvg + 2 * M * HID, vt);
    // attention (QBLK=64, permuted-K, in-register P) with fused o-norm + silu(gate) -> yg
    k_attn<<<1024, 256, 0, stream>>>(q_att, k_att, vt, qkvg + 3 * M * HID, ow, yg);
    // output projection (m97 128^2, fp32 out)
    k_gemm<<<dim3(32, 16, 1), 256, 0, stream>>>(yg, Wt + (size_t)4 * 2048 * 2048, (float*)d_out,
                                                (int)M, 2048, 2048);
}

// Round 17
// 308.368 us; speedup vs baseline: 1.0937x; 1.0198x over previous
//
#include <hip/hip_runtime.h>
#include <hip/hip_bf16.h>
#include <stdint.h>

typedef __bf16 bf16x8 __attribute__((ext_vector_type(8)));
typedef float f32x4 __attribute__((ext_vector_type(4)));
typedef __hip_bfloat16 bf16;

__device__ __forceinline__ void gload16(const void* g, void* l) {
    __builtin_amdgcn_global_load_lds(
        (const __attribute__((address_space(1))) uint32_t*)g,
        (__attribute__((address_space(3))) uint32_t*)l,
        16, 0, 0);
}

// ---------------- elementwise convert fp32 -> bf16 (x) ----------------
__global__ void k_cvt_bf16(const float* __restrict__ in, bf16* __restrict__ out, int n4) {
    int i = blockIdx.x * blockDim.x + threadIdx.x;
    if (i >= n4) return;
    float4 v = reinterpret_cast<const float4*>(in)[i];
    union { bf16 h[4]; uint2 u; } pk;
    pk.h[0] = __float2bfloat16(v.x);
    pk.h[1] = __float2bfloat16(v.y);
    pk.h[2] = __float2bfloat16(v.z);
    pk.h[3] = __float2bfloat16(v.w);
    reinterpret_cast<uint2*>(out)[i] = pk.u;
}

// ---------------- rope cos/sin table [T][128] (cos j | sin j) ----------------
__global__ void k_rope_tbl(float* __restrict__ tbl) {
    int i = blockIdx.x * blockDim.x + threadIdx.x; // T*64
    int t = i >> 6, j = i & 63;
    float inv = powf(10000.0f, -(float)j * (1.0f / 64.0f));
    float f = (float)t * inv;
    tbl[t * 128 + j] = cosf(f);
    tbl[t * 128 + 64 + j] = sinf(f);
}

// ---------------- weight transpose + convert: W[k][n] fp32 -> Wt[n][k] bf16 ----------------
__global__ void k_wtrans(const float* __restrict__ w0, const float* __restrict__ w1,
                         const float* __restrict__ w2, const float* __restrict__ w3,
                         const float* __restrict__ w4, bf16* __restrict__ out) {
    __shared__ float tile[64][65];
    const float* srcs[5] = {w0, w1, w2, w3, w4};
    const float* src = srcs[blockIdx.z];
    bf16* dst = out + (size_t)blockIdx.z * 2048 * 2048;
    int k0 = blockIdx.x * 64, n0 = blockIdx.y * 64;
    int tx = threadIdx.x, ty = threadIdx.y; // 64 x 4
#pragma unroll
    for (int i = 0; i < 16; i++)
        tile[ty + 4 * i][tx] = src[(size_t)(k0 + ty + 4 * i) * 2048 + n0 + tx];
    __syncthreads();
#pragma unroll
    for (int i = 0; i < 16; i++)
        dst[(size_t)(n0 + ty + 4 * i) * 2048 + k0 + tx] = __float2bfloat16(tile[tx][ty + 4 * i]);
}

// ---------------- GEMM 128x128 (m97-structure), used for the output projection ----------------
__global__ __launch_bounds__(256) void k_gemm(
    const bf16* __restrict__ A, const bf16* __restrict__ Bt, float* __restrict__ C,
    int M, int N, int K) {
    __shared__ __align__(16) bf16 As[128 * 64];
    __shared__ __align__(16) bf16 Bs[128 * 64];
    int lane = threadIdx.x & 63, wave = threadIdx.x >> 6;
    int g = lane >> 4, cc = lane & 15;
    int wr = wave >> 1, wc = wave & 1;
    size_t m0 = (size_t)blockIdx.x * 128, n0 = (size_t)blockIdx.y * 128;
    const bf16* Ab = A + m0 * K;
    const bf16* Bb = Bt + (size_t)blockIdx.z * N * K + n0 * K;
    float* Cb = C + (size_t)blockIdx.z * M * N + m0 * N + n0;

    f32x4 acc[4][4];
#pragma unroll
    for (int i = 0; i < 4; i++)
#pragma unroll
        for (int j = 0; j < 4; j++) acc[i][j] = {0.f, 0.f, 0.f, 0.f};

    int scol = (lane & 7) * 8;
    for (int k0 = 0; k0 < K; k0 += 64) {
#pragma unroll
        for (int i = 0; i < 4; i++) {
            int ch = wave * 4 + i;
            int row = ch * 8 + (lane >> 3);
            gload16(&Ab[(size_t)row * K + k0 + scol], &As[ch * 512]);
            gload16(&Bb[(size_t)row * K + k0 + scol], &Bs[ch * 512]);
        }
        __syncthreads();
#pragma unroll
        for (int kk = 0; kk < 2; kk++) {
            bf16x8 af[4], bfr[4];
#pragma unroll
            for (int m = 0; m < 4; m++)
                af[m] = *reinterpret_cast<const bf16x8*>(&As[(wr * 64 + m * 16 + cc) * 64 + kk * 32 + g * 8]);
#pragma unroll
            for (int n = 0; n < 4; n++)
                bfr[n] = *reinterpret_cast<const bf16x8*>(&Bs[(wc * 64 + n * 16 + cc) * 64 + kk * 32 + g * 8]);
#pragma unroll
            for (int m = 0; m < 4; m++)
#pragma unroll
                for (int n = 0; n < 4; n++)
                    acc[m][n] = __builtin_amdgcn_mfma_f32_16x16x32_bf16(af[m], bfr[n], acc[m][n], 0, 0, 0);
        }
        __syncthreads();
    }
#pragma unroll
    for (int m = 0; m < 4; m++)
#pragma unroll
        for (int n = 0; n < 4; n++)
#pragma unroll
            for (int r = 0; r < 4; r++) {
                size_t row = wr * 64 + m * 16 + g * 4 + r;
                Cb[row * N + (wc * 64 + n * 16 + cc)] = acc[m][n][r];
            }
}

// ---------------- GEMM 256x256 v2b (round-14 best): spread-read 4-phase, dbuf, bf16 out ----------------
__global__ __launch_bounds__(512, 2) void k_gemm256(
    const bf16* __restrict__ A, const bf16* __restrict__ Bt, bf16* __restrict__ C,
    int M, int N, int K) {
    __shared__ __align__(16) bf16 lds[2][8][64 * 64];
    const int tid = threadIdx.x;
    const int lane = tid & 63, wave = tid >> 6;
    const int g = lane >> 4, c = lane & 15, cx = c & 7;
    const int wr = wave >> 2, wc = wave & 3;  // 2M x 4N
    const int id = blockIdx.x;
    const int swz = (id & 7) * 64 + (id >> 3);
    const int xt = swz & 15, yt = (swz >> 4) & 7, zt = swz >> 7;
    const size_t m0 = (size_t)xt * 256, n0 = (size_t)yt * 256;
    const bf16* Ab = A + m0 * K;
    const bf16* Bb = Bt + (size_t)zt * (size_t)N * K + n0 * K;
    bf16* Cb = C + (size_t)zt * (size_t)M * N + m0 * N + n0;
    const int nt = K >> 6;

    const int srow = tid >> 3;
    const int scol = ((tid & 7) ^ (srow & 7)) * 8;

    auto stage = [&](int u, int q) {
        if (u >= nt) return;
        const bf16* src = (q < 4) ? &Ab[(size_t)(q * 64 + srow) * K]
                                  : &Bb[(size_t)((q - 4) * 64 + srow) * K];
        gload16(&src[((size_t)u << 6) + scol], &lds[u & 1][q][wave * 512]);
    };

    f32x4 acc[8][4];
#pragma unroll
    for (int i = 0; i < 8; i++)
#pragma unroll
        for (int j = 0; j < 4; j++) acc[i][j] = {0.f, 0.f, 0.f, 0.f};

#pragma unroll
    for (int q = 0; q < 8; q++) stage(0, q);
    stage(1, 0); stage(1, 2); stage(1, 4); stage(1, 5); stage(1, 6); stage(1, 7);
    asm volatile("s_waitcnt vmcnt(6)" ::: "memory");
    __builtin_amdgcn_s_barrier();

    bf16x8 afr[4][2], bfr[2][2][2];

#define READ_A(mh)                                                                   \
    do {                                                                             \
        const bf16* aq = &lds[t & 1][wr * 2 + (mh)][0];                              \
        _Pragma("unroll") for (int m_ = 0; m_ < 4; m_++)                             \
            _Pragma("unroll") for (int kh = 0; kh < 2; kh++)                         \
                afr[m_][kh] = *reinterpret_cast<const bf16x8*>(                      \
                    aq + (m_ * 16 + c) * 64 + ((kh * 4 + g) ^ cx) * 8);              \
    } while (0)
#define READ_B(nh)                                                                   \
    do {                                                                             \
        const bf16* bq = &lds[t & 1][4 + wc][0];                                     \
        _Pragma("unroll") for (int n_ = 0; n_ < 2; n_++)                             \
            _Pragma("unroll") for (int kh = 0; kh < 2; kh++)                         \
                bfr[nh][n_][kh] = *reinterpret_cast<const bf16x8*>(                  \
                    bq + (((nh)*2 + n_) * 16 + c) * 64 + ((kh * 4 + g) ^ cx) * 8);   \
    } while (0)
#define QUAD(mh, nh)                                                                 \
    do {                                                                             \
        __builtin_amdgcn_s_setprio(1);                                               \
        _Pragma("unroll") for (int kh = 0; kh < 2; kh++)                             \
            _Pragma("unroll") for (int m_ = 0; m_ < 4; m_++)                         \
                _Pragma("unroll") for (int n_ = 0; n_ < 2; n_++)                     \
                    acc[(mh)*4 + m_][(nh)*2 + n_] =                                  \
                        __builtin_amdgcn_mfma_f32_16x16x32_bf16(                     \
                            afr[m_][kh], bfr[nh][n_][kh],                            \
                            acc[(mh)*4 + m_][(nh)*2 + n_], 0, 0, 0);                 \
        __builtin_amdgcn_s_setprio(0);                                               \
    } while (0)

    for (int t = 0; t < nt; ++t) {
        // ---- ph1 ----
        READ_A(0);
        READ_B(0);
        stage(t + 1, 1); stage(t + 1, 3);
        __builtin_amdgcn_s_barrier();
        QUAD(0, 0);
        __builtin_amdgcn_s_barrier();
        // ---- ph2 ----
        READ_B(1);
        stage(t + 2, 0); stage(t + 2, 2);
        __builtin_amdgcn_s_barrier();
        QUAD(0, 1);
        __builtin_amdgcn_s_barrier();
        // ---- ph3 ----
        READ_A(1);
        stage(t + 2, 4); stage(t + 2, 5);
        __builtin_amdgcn_s_barrier();
        QUAD(1, 0);
        __builtin_amdgcn_s_barrier();
        // ---- ph4 ----
        stage(t + 2, 6); stage(t + 2, 7);
        if (t < nt - 2) asm volatile("s_waitcnt vmcnt(6)" ::: "memory");
        else            asm volatile("s_waitcnt vmcnt(0)" ::: "memory");
        __builtin_amdgcn_s_barrier();
        QUAD(1, 1);
        __builtin_amdgcn_s_barrier();
    }
#undef READ_A
#undef READ_B
#undef QUAD
#pragma unroll
    for (int m_ = 0; m_ < 8; m_++)
#pragma unroll
        for (int n_ = 0; n_ < 4; n_++)
#pragma unroll
            for (int r_ = 0; r_ < 4; r_++) {
                size_t row = wr * 128 + m_ * 16 + g * 4 + r_;
                Cb[row * N + wc * 64 + n_ * 16 + c] = __float2bfloat16(acc[m_][n_][r_]);
            }
}

// ---------------- RoPE + per-head RMS norm, VECTORIZED (bf16x8 loads, 16B/lane) ----------------
// One wave per (bt, head-quad). Lane l owns 8 elems jj..jj+7 (jj=8*(l&7)) of head l>>4;
// bit3 of l selects the half (d<64 vs d>=64). Rotate partner exchanged via shfl_xor(.,8).
// RMS reduce = shfl_xor{1,2,4,8} over the 16-lane head group.
__global__ void k_rope_rms(const bf16* __restrict__ src_q, const bf16* __restrict__ src_k,
                           const float* __restrict__ qw, const float* __restrict__ kw,
                           const float* __restrict__ tbl, bf16* __restrict__ dst_q,
                           bf16* __restrict__ dst_k) {
    const int T = 2048;
    int role = blockIdx.y;
    const bf16* src = role ? src_k : src_q;
    const float* rmsw = role ? kw : qw;
    bf16* dst = role ? dst_k : dst_q;
    float outscale = role ? 1.0f : 0.08838834764831845f;
    int wv = blockIdx.x * 4 + (threadIdx.x >> 6);  // (bt, hq) over B*T*4
    int lane = threadIdx.x & 63;
    int hq = wv & 3, bt = wv >> 2;
    int t = bt & (T - 1), b_ = bt >> 11;
    int hsub = lane >> 4;
    int half = (lane >> 3) & 1;
    int jj = (lane & 7) * 8;

    bf16x8 v = *reinterpret_cast<const bf16x8*>(
        src + (size_t)bt * 2048 + hq * 512 + lane * 8);
    float f[8], g[8];
#pragma unroll
    for (int j = 0; j < 8; j++) f[j] = (float)v[j];
#pragma unroll
    for (int j = 0; j < 8; j++) g[j] = __shfl_xor(f[j], 8, 64);

    const float* tb = tbl + t * 128;
    float4 c0 = *reinterpret_cast<const float4*>(&tb[jj]);
    float4 c1 = *reinterpret_cast<const float4*>(&tb[jj + 4]);
    float4 s0 = *reinterpret_cast<const float4*>(&tb[64 + jj]);
    float4 s1 = *reinterpret_cast<const float4*>(&tb[64 + jj + 4]);
    float cs[8] = {c0.x, c0.y, c0.z, c0.w, c1.x, c1.y, c1.z, c1.w};
    float sn[8] = {s0.x, s0.y, s0.z, s0.w, s1.x, s1.y, s1.z, s1.w};

    float out[8];
    float ssum = 0.f;
#pragma unroll
    for (int j = 0; j < 8; j++) {
        float a = half ? g[j] : f[j];   // x[jj+j]
        float b = half ? f[j] : g[j];   // x[jj+j+64]
        float o = half ? (a * sn[j] + b * cs[j]) : (a * cs[j] - b * sn[j]);
        out[j] = o;
        ssum += o * o;
    }
    ssum += __shfl_xor(ssum, 1, 64);
    ssum += __shfl_xor(ssum, 2, 64);
    ssum += __shfl_xor(ssum, 4, 64);
    ssum += __shfl_xor(ssum, 8, 64);
    float rs = rsqrtf(ssum * (1.0f / 128.0f) + 1e-5f) * outscale;

    int d0 = half * 64 + jj;
    float4 w0 = *reinterpret_cast<const float4*>(&rmsw[d0]);
    float4 w1 = *reinterpret_cast<const float4*>(&rmsw[d0 + 4]);
    float wv8[8] = {w0.x, w0.y, w0.z, w0.w, w1.x, w1.y, w1.z, w1.w};
    union { bf16 h[8]; uint4 u; } pk;
#pragma unroll
    for (int j = 0; j < 8; j++) pk.h[j] = __float2bfloat16(out[j] * rs * wv8[j]);
    int h = hq * 4 + hsub;
    size_t o = ((size_t)(b_ * 16 + h) * T + t) * 128 + d0;
    *reinterpret_cast<uint4*>(dst + o) = pk.u;
}

// ---------------- V transpose 64x64: bf16 [B*T][2048] -> bf16 Vt [BH][128][T] ----------------
__global__ void k_vtrans(const bf16* __restrict__ V, bf16* __restrict__ Vt) {
    const int T = 2048;
    __shared__ float tile[64][65];
    int bh = blockIdx.z, b_ = bh >> 4, h = bh & 15;
    int t0 = blockIdx.x * 64, d0 = blockIdx.y * 64;
    int tx = threadIdx.x, ty = threadIdx.y; // 64 x 4
#pragma unroll
    for (int i = 0; i < 16; i++)
        tile[ty + 4 * i][tx] =
            __bfloat162float(V[((size_t)(b_ * T + t0 + ty + 4 * i)) * 2048 + h * 128 + d0 + tx]);
    __syncthreads();
#pragma unroll
    for (int i = 0; i < 16; i++)
        Vt[((size_t)bh * 128 + d0 + ty + 4 * i) * T + t0 + tx] = __float2bfloat16(tile[tx][ty + 4 * i]);
}

// ---------------- causal flash attention v6: QBLK=64, permuted-K, in-reg P ----------------
__global__ __launch_bounds__(256) void k_attn(
    const bf16* __restrict__ Q, const bf16* __restrict__ K,
    const bf16* __restrict__ Vt, const bf16* __restrict__ gate,
    const float* __restrict__ ow, bf16* __restrict__ out) {
    const int T = 2048;
    __shared__ __align__(16) bf16 KsB[2][64 * 128];
    __shared__ __align__(16) bf16 VsB[2][128 * 64];
    int lane = threadIdx.x & 63, wave = threadIdx.x >> 6;
    int g = lane >> 4, c = lane & 15;
    int wg = blockIdx.x;
    int bh = wg & 31;          // XCD = wg%8 = bh%8 -> 4 heads per XCD (K+V = 4MB = one L2)
    int qt = 31 - (wg >> 5);   // heavy q-tiles launch first
    int q0 = qt * 64;
    const bf16* Qb = Q + (size_t)bh * T * 128;
    const bf16* Kb = K + (size_t)bh * T * 128;
    const bf16* Vb = Vt + (size_t)bh * 128 * T;

    int qrow = q0 + wave * 16 + c;
    bf16x8 qf[4];
#pragma unroll
    for (int kk = 0; kk < 4; kk++)
        qf[kk] = *reinterpret_cast<const bf16x8*>(&Qb[(size_t)qrow * 128 + kk * 32 + g * 8]);

    // staging constants: 4 waves x 4 chunks each for K and V; K rows permuted
    int kprow[4], klu[4], vrow[4], vlu[4];
#pragma unroll
    for (int i = 0; i < 4; i++) {
        int ch = wave * 4 + i;
        int p = ch * 4 + (lane >> 4);                       // staged K row position 0..63
        kprow[i] = ((p >> 5) & 1) * 32 + ((p >> 2) & 3) * 8 + ((p >> 4) & 1) * 4 + (p & 3);
        klu[i] = (lane & 15) ^ (p & 7);
        vrow[i] = ch * 8 + (lane >> 3);                     // V d-row 0..127 (linear)
        vlu[i] = (lane & 7) ^ (vrow[i] & 7);
    }
    auto stage = [&](int kv0, int b) {
#pragma unroll
        for (int i = 0; i < 4; i++) {
            int ch = wave * 4 + i;
            gload16(&Kb[(size_t)(kv0 + kprow[i]) * 128 + klu[i] * 8], &KsB[b][ch * 512]);
            gload16(&Vb[(size_t)vrow[i] * T + kv0 + vlu[i] * 8], &VsB[b][ch * 512]);
        }
    };

    f32x4 acc[8];
#pragma unroll
    for (int i = 0; i < 8; i++) acc[i] = {0.f, 0.f, 0.f, 0.f};
    float m = -INFINITY, l = 0.f;

    int ntiles = qt + 1;
    stage(0, 0);
    __syncthreads();
    int cur = 0;
    for (int it = 0; it < ntiles; ++it) {
        int kv0 = it * 64;
        if (it + 1 < ntiles) stage(kv0 + 64, cur ^ 1);
        const bf16* Ks = KsB[cur];
        const bf16* Vs = VsB[cur];

        f32x4 s[4];
#pragma unroll
        for (int nf = 0; nf < 4; nf++) s[nf] = {0.f, 0.f, 0.f, 0.f};
#pragma unroll
        for (int nf = 0; nf < 4; nf++)
#pragma unroll
            for (int kk = 0; kk < 4; kk++) {
                int pu = (kk * 4 + g) ^ (c & 7);
                bf16x8 kf = *reinterpret_cast<const bf16x8*>(&Ks[(nf * 16 + c) * 128 + pu * 8]);
                s[nf] = __builtin_amdgcn_mfma_f32_16x16x32_bf16(kf, qf[kk], s[nf], 0, 0, 0);
            }
        // causal mask on the permuted true kv: kv_true = kv0 + 32*(nf>>1) + 8g + 4*(nf&1) + r
        if (it == ntiles - 1) {
#pragma unroll
            for (int nf = 0; nf < 4; nf++)
#pragma unroll
                for (int r = 0; r < 4; r++)
                    if (kv0 + (nf >> 1) * 32 + g * 8 + (nf & 1) * 4 + r > qrow)
                        s[nf][r] = -1e30f;
        }
        float mx = -INFINITY;
#pragma unroll
        for (int nf = 0; nf < 4; nf++)
#pragma unroll
            for (int r = 0; r < 4; r++) mx = fmaxf(mx, s[nf][r]);
        mx = fmaxf(mx, __shfl_xor(mx, 16, 64));
        mx = fmaxf(mx, __shfl_xor(mx, 32, 64));
        if (__all(mx - m <= 8.0f)) {  // T13 defer-max
            float rsum = 0.f;
#pragma unroll
            for (int nf = 0; nf < 4; nf++)
#pragma unroll
                for (int r = 0; r < 4; r++) {
                    float p = __expf(s[nf][r] - m);
                    s[nf][r] = p;
                    rsum += p;
                }
            rsum += __shfl_xor(rsum, 16, 64);
            rsum += __shfl_xor(rsum, 32, 64);
            l += rsum;
        } else {
            float mnew = fmaxf(m, mx);
            float alpha = __expf(m - mnew);
            m = mnew;
            float rsum = 0.f;
#pragma unroll
            for (int nf = 0; nf < 4; nf++)
#pragma unroll
                for (int r = 0; r < 4; r++) {
                    float p = __expf(s[nf][r] - mnew);
                    s[nf][r] = p;
                    rsum += p;
                }
            rsum += __shfl_xor(rsum, 16, 64);
            rsum += __shfl_xor(rsum, 32, 64);
            l = l * alpha + rsum;
            float al[4];
#pragma unroll
            for (int r = 0; r < 4; r++) al[r] = __shfl(alpha, g * 4 + r, 64);
#pragma unroll
            for (int nf = 0; nf < 8; nf++)
#pragma unroll
                for (int r = 0; r < 4; r++) acc[nf][r] *= al[r];
        }
        // PV: A-frag fully in-register (permuted-K QK^T layout)
#pragma unroll
        for (int kk2 = 0; kk2 < 2; kk2++) {
            union { bf16 h[8]; bf16x8 v; } pf;
#pragma unroll
            for (int r = 0; r < 4; r++) {
                pf.h[r] = __float2bfloat16(s[2 * kk2][r]);
                pf.h[4 + r] = __float2bfloat16(s[2 * kk2 + 1][r]);
            }
#pragma unroll
            for (int nf = 0; nf < 8; nf++) {
                int pu = (kk2 * 4 + g) ^ (c & 7);
                bf16x8 vf = *reinterpret_cast<const bf16x8*>(&Vs[(nf * 16 + c) * 64 + pu * 8]);
                acc[nf] = __builtin_amdgcn_mfma_f32_16x16x32_bf16(pf.v, vf, acc[nf], 0, 0, 0);
            }
        }
        __syncthreads();
        cur ^= 1;
    }
    // ---- fused epilogue: 1/l, o-norm, silu(gate) ----
    float inv = 1.0f / l;
    float iv[4];
#pragma unroll
    for (int r = 0; r < 4; r++) iv[r] = __shfl(inv, g * 4 + r, 64);
    int b_ = bh >> 4, h = bh & 15;
    float owv[8];
#pragma unroll
    for (int nf = 0; nf < 8; nf++) owv[nf] = ow[nf * 16 + c];
#pragma unroll
    for (int r = 0; r < 4; r++) {
        int row = q0 + wave * 16 + g * 4 + r;
        float y[8];
        float ss = 0.f;
#pragma unroll
        for (int nf = 0; nf < 8; nf++) {
            y[nf] = acc[nf][r] * iv[r];
            ss += y[nf] * y[nf];
        }
        ss += __shfl_xor(ss, 1, 64);
        ss += __shfl_xor(ss, 2, 64);
        ss += __shfl_xor(ss, 4, 64);
        ss += __shfl_xor(ss, 8, 64);
        float rs = rsqrtf(ss * (1.0f / 128.0f) + 1e-5f);
        size_t gi = ((size_t)(b_ * T + row)) * 2048 + h * 128;
#pragma unroll
        for (int nf = 0; nf < 8; nf++) {
            int col = nf * 16 + c;
            float gv = __bfloat162float(gate[gi + col]);
            gv = gv / (1.f + __expf(-gv));
            out[gi + col] = __float2bfloat16(y[nf] * rs * owv[nf] * gv);
        }
    }
}

extern "C" void kernel_launch(void* const* d_in, const int* in_sizes, int n_in,
                              void* d_out, int out_size, void* d_ws, size_t ws_size,
                              hipStream_t stream) {
    const float* x  = (const float*)d_in[0];
    const float* Wq = (const float*)d_in[1];
    const float* Wk = (const float*)d_in[2];
    const float* Wv = (const float*)d_in[3];
    const float* Wg = (const float*)d_in[4];
    const float* Wo = (const float*)d_in[5];
    const float* qw = (const float*)d_in[6];
    const float* kw = (const float*)d_in[7];
    const float* ow = (const float*)d_in[8];

    const size_t M = 4096, HID = 2048;
    char* w = (char*)d_ws;
    bf16*  xb    = (bf16*)(w);                     // @0          16,777,216 B
    bf16*  Wt    = (bf16*)(w + 16777216);          // @16M        41,943,040 B [5][2048][2048]
    bf16*  qkvg  = (bf16*)(w + 58720256);          // @56M        67,108,864 B [4][4096][2048] bf16
    bf16*  q_att = (bf16*)(w + 125829120);         //             16,777,216 B [32][2048][128]
    bf16*  k_att = (bf16*)(w + 142606336);         //             16,777,216 B
    bf16*  vt    = (bf16*)(w + 159383552);         //             16,777,216 B [32][128][2048]
    float* tbl   = (float*)(w + 176160768);        //              1,048,576 B [2048][128]
    bf16*  yg    = (bf16*)(w + 177209344);         //             16,777,216 B [B*T][2048]

    k_cvt_bf16<<<8192, 256, 0, stream>>>(x, xb, (int)(M * HID / 4));
    k_rope_tbl<<<512, 256, 0, stream>>>(tbl);
    k_wtrans<<<dim3(32, 32, 5), dim3(64, 4), 0, stream>>>(Wq, Wk, Wv, Wg, Wo, Wt);
    // fused Q/K/V/Gate projection (v2b: best measured, 150us / 41% MfmaUtil)
    k_gemm256<<<512, 512, 0, stream>>>(xb, Wt, qkvg, (int)M, 2048, 2048);
    // rope + rms for q and k in one launch, vectorized bf16x8 (+ fold 1/sqrt(D) into q)
    k_rope_rms<<<dim3(4096, 2), 256, 0, stream>>>(qkvg, qkvg + M * HID, qw, kw, tbl,
                                                  q_att, k_att);
    k_vtrans<<<dim3(32, 2, 32), dim3(64, 4), 0, stream>>>(qkvg + 2 * M * HID, vt);
    // attention (QBLK=64, permuted-K, in-register P) with fused o-norm + silu(gate) -> yg
    k_attn<<<1024, 256, 0, stream>>>(q_att, k_att, vt, qkvg + 3 * M * HID, ow, yg);
    // output projection (m97 128^2, fp32 out)
    k_gemm<<<dim3(32, 16, 1), 256, 0, stream>>>(yg, Wt + (size_t)4 * 2048 * 2048, (float*)d_out,
                                                (int)M, 2048, 2048);
}

// Round 18
// 304.726 us; speedup vs baseline: 1.1068x; 1.0120x over previous
//
#include <hip/hip_runtime.h>
#include <hip/hip_bf16.h>
#include <stdint.h>

typedef __bf16 bf16x8 __attribute__((ext_vector_type(8)));
typedef float f32x4 __attribute__((ext_vector_type(4)));
typedef __hip_bfloat16 bf16;

__device__ __forceinline__ void gload16(const void* g, void* l) {
    __builtin_amdgcn_global_load_lds(
        (const __attribute__((address_space(1))) uint32_t*)g,
        (__attribute__((address_space(3))) uint32_t*)l,
        16, 0, 0);
}

// ---------------- elementwise convert fp32 -> bf16 (x) ----------------
__global__ void k_cvt_bf16(const float* __restrict__ in, bf16* __restrict__ out, int n4) {
    int i = blockIdx.x * blockDim.x + threadIdx.x;
    if (i >= n4) return;
    float4 v = reinterpret_cast<const float4*>(in)[i];
    union { bf16 h[4]; uint2 u; } pk;
    pk.h[0] = __float2bfloat16(v.x);
    pk.h[1] = __float2bfloat16(v.y);
    pk.h[2] = __float2bfloat16(v.z);
    pk.h[3] = __float2bfloat16(v.w);
    reinterpret_cast<uint2*>(out)[i] = pk.u;
}

// ---------------- rope cos/sin table [T][128] (cos j | sin j) ----------------
__global__ void k_rope_tbl(float* __restrict__ tbl) {
    int i = blockIdx.x * blockDim.x + threadIdx.x; // T*64
    int t = i >> 6, j = i & 63;
    float inv = powf(10000.0f, -(float)j * (1.0f / 64.0f));
    float f = (float)t * inv;
    tbl[t * 128 + j] = cosf(f);
    tbl[t * 128 + 64 + j] = sinf(f);
}

// ---------------- weight transpose + convert: W[k][n] fp32 -> Wt[n][k] bf16 ----------------
__global__ void k_wtrans(const float* __restrict__ w0, const float* __restrict__ w1,
                         const float* __restrict__ w2, const float* __restrict__ w3,
                         const float* __restrict__ w4, bf16* __restrict__ out) {
    __shared__ float tile[64][65];
    const float* srcs[5] = {w0, w1, w2, w3, w4};
    const float* src = srcs[blockIdx.z];
    bf16* dst = out + (size_t)blockIdx.z * 2048 * 2048;
    int k0 = blockIdx.x * 64, n0 = blockIdx.y * 64;
    int tx = threadIdx.x, ty = threadIdx.y; // 64 x 4
#pragma unroll
    for (int i = 0; i < 16; i++)
        tile[ty + 4 * i][tx] = src[(size_t)(k0 + ty + 4 * i) * 2048 + n0 + tx];
    __syncthreads();
#pragma unroll
    for (int i = 0; i < 16; i++)
        dst[(size_t)(n0 + ty + 4 * i) * 2048 + k0 + tx] = __float2bfloat16(tile[tx][ty + 4 * i]);
}

// ---------------- GEMM 128x128 (m97-structure), used for the output projection ----------------
__global__ __launch_bounds__(256) void k_gemm(
    const bf16* __restrict__ A, const bf16* __restrict__ Bt, float* __restrict__ C,
    int M, int N, int K) {
    __shared__ __align__(16) bf16 As[128 * 64];
    __shared__ __align__(16) bf16 Bs[128 * 64];
    int lane = threadIdx.x & 63, wave = threadIdx.x >> 6;
    int g = lane >> 4, cc = lane & 15;
    int wr = wave >> 1, wc = wave & 1;
    size_t m0 = (size_t)blockIdx.x * 128, n0 = (size_t)blockIdx.y * 128;
    const bf16* Ab = A + m0 * K;
    const bf16* Bb = Bt + (size_t)blockIdx.z * N * K + n0 * K;
    float* Cb = C + (size_t)blockIdx.z * M * N + m0 * N + n0;

    f32x4 acc[4][4];
#pragma unroll
    for (int i = 0; i < 4; i++)
#pragma unroll
        for (int j = 0; j < 4; j++) acc[i][j] = {0.f, 0.f, 0.f, 0.f};

    int scol = (lane & 7) * 8;
    for (int k0 = 0; k0 < K; k0 += 64) {
#pragma unroll
        for (int i = 0; i < 4; i++) {
            int ch = wave * 4 + i;
            int row = ch * 8 + (lane >> 3);
            gload16(&Ab[(size_t)row * K + k0 + scol], &As[ch * 512]);
            gload16(&Bb[(size_t)row * K + k0 + scol], &Bs[ch * 512]);
        }
        __syncthreads();
#pragma unroll
        for (int kk = 0; kk < 2; kk++) {
            bf16x8 af[4], bfr[4];
#pragma unroll
            for (int m = 0; m < 4; m++)
                af[m] = *reinterpret_cast<const bf16x8*>(&As[(wr * 64 + m * 16 + cc) * 64 + kk * 32 + g * 8]);
#pragma unroll
            for (int n = 0; n < 4; n++)
                bfr[n] = *reinterpret_cast<const bf16x8*>(&Bs[(wc * 64 + n * 16 + cc) * 64 + kk * 32 + g * 8]);
#pragma unroll
            for (int m = 0; m < 4; m++)
#pragma unroll
                for (int n = 0; n < 4; n++)
                    acc[m][n] = __builtin_amdgcn_mfma_f32_16x16x32_bf16(af[m], bfr[n], acc[m][n], 0, 0, 0);
        }
        __syncthreads();
    }
#pragma unroll
    for (int m = 0; m < 4; m++)
#pragma unroll
        for (int n = 0; n < 4; n++)
#pragma unroll
            for (int r = 0; r < 4; r++) {
                size_t row = wr * 64 + m * 16 + g * 4 + r;
                Cb[row * N + (wc * 64 + n * 16 + cc)] = acc[m][n][r];
            }
}

// ---------------- GEMM 256x256 v2c: v2b minus the 4 pre-QUAD barriers ----------------
// Regions are now delimited only by the trailing (post-QUAD) barriers, letting waves slip
// by a sub-phase so one wave's MFMA burst covers another's ds_read burst. WAR audit:
// every stage targets a quarter whose last reads were consumed by that region's own QUAD
// before the issuing wave reached the preceding barrier (reads feed MFMAs -> lgkm-waited).
// vmcnt is per-wave and precedes the trailing barrier as before.
__global__ __launch_bounds__(512, 2) void k_gemm256(
    const bf16* __restrict__ A, const bf16* __restrict__ Bt, bf16* __restrict__ C,
    int M, int N, int K) {
    __shared__ __align__(16) bf16 lds[2][8][64 * 64];
    const int tid = threadIdx.x;
    const int lane = tid & 63, wave = tid >> 6;
    const int g = lane >> 4, c = lane & 15, cx = c & 7;
    const int wr = wave >> 2, wc = wave & 3;  // 2M x 4N
    const int id = blockIdx.x;
    const int swz = (id & 7) * 64 + (id >> 3);
    const int xt = swz & 15, yt = (swz >> 4) & 7, zt = swz >> 7;
    const size_t m0 = (size_t)xt * 256, n0 = (size_t)yt * 256;
    const bf16* Ab = A + m0 * K;
    const bf16* Bb = Bt + (size_t)zt * (size_t)N * K + n0 * K;
    bf16* Cb = C + (size_t)zt * (size_t)M * N + m0 * N + n0;
    const int nt = K >> 6;

    const int srow = tid >> 3;
    const int scol = ((tid & 7) ^ (srow & 7)) * 8;

    auto stage = [&](int u, int q) {
        if (u >= nt) return;
        const bf16* src = (q < 4) ? &Ab[(size_t)(q * 64 + srow) * K]
                                  : &Bb[(size_t)((q - 4) * 64 + srow) * K];
        gload16(&src[((size_t)u << 6) + scol], &lds[u & 1][q][wave * 512]);
    };

    f32x4 acc[8][4];
#pragma unroll
    for (int i = 0; i < 8; i++)
#pragma unroll
        for (int j = 0; j < 4; j++) acc[i][j] = {0.f, 0.f, 0.f, 0.f};

#pragma unroll
    for (int q = 0; q < 8; q++) stage(0, q);
    stage(1, 0); stage(1, 2); stage(1, 4); stage(1, 5); stage(1, 6); stage(1, 7);
    asm volatile("s_waitcnt vmcnt(6)" ::: "memory");
    __builtin_amdgcn_s_barrier();

    bf16x8 afr[4][2], bfr[2][2][2];

#define READ_A(mh)                                                                   \
    do {                                                                             \
        const bf16* aq = &lds[t & 1][wr * 2 + (mh)][0];                              \
        _Pragma("unroll") for (int m_ = 0; m_ < 4; m_++)                             \
            _Pragma("unroll") for (int kh = 0; kh < 2; kh++)                         \
                afr[m_][kh] = *reinterpret_cast<const bf16x8*>(                      \
                    aq + (m_ * 16 + c) * 64 + ((kh * 4 + g) ^ cx) * 8);              \
    } while (0)
#define READ_B(nh)                                                                   \
    do {                                                                             \
        const bf16* bq = &lds[t & 1][4 + wc][0];                                     \
        _Pragma("unroll") for (int n_ = 0; n_ < 2; n_++)                             \
            _Pragma("unroll") for (int kh = 0; kh < 2; kh++)                         \
                bfr[nh][n_][kh] = *reinterpret_cast<const bf16x8*>(                  \
                    bq + (((nh)*2 + n_) * 16 + c) * 64 + ((kh * 4 + g) ^ cx) * 8);   \
    } while (0)
#define QUAD(mh, nh)                                                                 \
    do {                                                                             \
        __builtin_amdgcn_s_setprio(1);                                               \
        _Pragma("unroll") for (int kh = 0; kh < 2; kh++)                             \
            _Pragma("unroll") for (int m_ = 0; m_ < 4; m_++)                         \
                _Pragma("unroll") for (int n_ = 0; n_ < 2; n_++)                     \
                    acc[(mh)*4 + m_][(nh)*2 + n_] =                                  \
                        __builtin_amdgcn_mfma_f32_16x16x32_bf16(                     \
                            afr[m_][kh], bfr[nh][n_][kh],                            \
                            acc[(mh)*4 + m_][(nh)*2 + n_], 0, 0, 0);                 \
        __builtin_amdgcn_s_setprio(0);                                               \
    } while (0)

    for (int t = 0; t < nt; ++t) {
        // ---- R1: reads + stage + MFMA co-scheduled; barrier only at region end ----
        READ_A(0);
        READ_B(0);
        stage(t + 1, 1); stage(t + 1, 3);
        QUAD(0, 0);
        __builtin_amdgcn_s_barrier();
        // ---- R2 ----
        READ_B(1);
        stage(t + 2, 0); stage(t + 2, 2);
        QUAD(0, 1);
        __builtin_amdgcn_s_barrier();
        // ---- R3 ----
        READ_A(1);
        stage(t + 2, 4); stage(t + 2, 5);
        QUAD(1, 0);
        __builtin_amdgcn_s_barrier();
        // ---- R4 ----
        stage(t + 2, 6); stage(t + 2, 7);
        if (t < nt - 2) asm volatile("s_waitcnt vmcnt(6)" ::: "memory");
        else            asm volatile("s_waitcnt vmcnt(0)" ::: "memory");
        QUAD(1, 1);
        __builtin_amdgcn_s_barrier();
    }
#undef READ_A
#undef READ_B
#undef QUAD
#pragma unroll
    for (int m_ = 0; m_ < 8; m_++)
#pragma unroll
        for (int n_ = 0; n_ < 4; n_++)
#pragma unroll
            for (int r_ = 0; r_ < 4; r_++) {
                size_t row = wr * 128 + m_ * 16 + g * 4 + r_;
                Cb[row * N + wc * 64 + n_ * 16 + c] = __float2bfloat16(acc[m_][n_][r_]);
            }
}

// ---------------- RoPE + per-head RMS norm, VECTORIZED (bf16x8 loads, 16B/lane) ----------------
__global__ void k_rope_rms(const bf16* __restrict__ src_q, const bf16* __restrict__ src_k,
                           const float* __restrict__ qw, const float* __restrict__ kw,
                           const float* __restrict__ tbl, bf16* __restrict__ dst_q,
                           bf16* __restrict__ dst_k) {
    const int T = 2048;
    int role = blockIdx.y;
    const bf16* src = role ? src_k : src_q;
    const float* rmsw = role ? kw : qw;
    bf16* dst = role ? dst_k : dst_q;
    float outscale = role ? 1.0f : 0.08838834764831845f;
    int wv = blockIdx.x * 4 + (threadIdx.x >> 6);  // (bt, hq) over B*T*4
    int lane = threadIdx.x & 63;
    int hq = wv & 3, bt = wv >> 2;
    int t = bt & (T - 1), b_ = bt >> 11;
    int hsub = lane >> 4;
    int half = (lane >> 3) & 1;
    int jj = (lane & 7) * 8;

    bf16x8 v = *reinterpret_cast<const bf16x8*>(
        src + (size_t)bt * 2048 + hq * 512 + lane * 8);
    float f[8], g[8];
#pragma unroll
    for (int j = 0; j < 8; j++) f[j] = (float)v[j];
#pragma unroll
    for (int j = 0; j < 8; j++) g[j] = __shfl_xor(f[j], 8, 64);

    const float* tb = tbl + t * 128;
    float4 c0 = *reinterpret_cast<const float4*>(&tb[jj]);
    float4 c1 = *reinterpret_cast<const float4*>(&tb[jj + 4]);
    float4 s0 = *reinterpret_cast<const float4*>(&tb[64 + jj]);
    float4 s1 = *reinterpret_cast<const float4*>(&tb[64 + jj + 4]);
    float cs[8] = {c0.x, c0.y, c0.z, c0.w, c1.x, c1.y, c1.z, c1.w};
    float sn[8] = {s0.x, s0.y, s0.z, s0.w, s1.x, s1.y, s1.z, s1.w};

    float out[8];
    float ssum = 0.f;
#pragma unroll
    for (int j = 0; j < 8; j++) {
        float a = half ? g[j] : f[j];   // x[jj+j]
        float b = half ? f[j] : g[j];   // x[jj+j+64]
        float o = half ? (a * sn[j] + b * cs[j]) : (a * cs[j] - b * sn[j]);
        out[j] = o;
        ssum += o * o;
    }
    ssum += __shfl_xor(ssum, 1, 64);
    ssum += __shfl_xor(ssum, 2, 64);
    ssum += __shfl_xor(ssum, 4, 64);
    ssum += __shfl_xor(ssum, 8, 64);
    float rs = rsqrtf(ssum * (1.0f / 128.0f) + 1e-5f) * outscale;

    int d0 = half * 64 + jj;
    float4 w0 = *reinterpret_cast<const float4*>(&rmsw[d0]);
    float4 w1 = *reinterpret_cast<const float4*>(&rmsw[d0 + 4]);
    float wv8[8] = {w0.x, w0.y, w0.z, w0.w, w1.x, w1.y, w1.z, w1.w};
    union { bf16 h[8]; uint4 u; } pk;
#pragma unroll
    for (int j = 0; j < 8; j++) pk.h[j] = __float2bfloat16(out[j] * rs * wv8[j]);
    int h = hq * 4 + hsub;
    size_t o = ((size_t)(b_ * 16 + h) * T + t) * 128 + d0;
    *reinterpret_cast<uint4*>(dst + o) = pk.u;
}

// ---------------- V transpose 64x64: bf16 [B*T][2048] -> bf16 Vt [BH][128][T] ----------------
__global__ void k_vtrans(const bf16* __restrict__ V, bf16* __restrict__ Vt) {
    const int T = 2048;
    __shared__ float tile[64][65];
    int bh = blockIdx.z, b_ = bh >> 4, h = bh & 15;
    int t0 = blockIdx.x * 64, d0 = blockIdx.y * 64;
    int tx = threadIdx.x, ty = threadIdx.y; // 64 x 4
#pragma unroll
    for (int i = 0; i < 16; i++)
        tile[ty + 4 * i][tx] =
            __bfloat162float(V[((size_t)(b_ * T + t0 + ty + 4 * i)) * 2048 + h * 128 + d0 + tx]);
    __syncthreads();
#pragma unroll
    for (int i = 0; i < 16; i++)
        Vt[((size_t)bh * 128 + d0 + ty + 4 * i) * T + t0 + tx] = __float2bfloat16(tile[tx][ty + 4 * i]);
}

// ---------------- causal flash attention v6: QBLK=64, permuted-K, in-reg P ----------------
__global__ __launch_bounds__(256) void k_attn(
    const bf16* __restrict__ Q, const bf16* __restrict__ K,
    const bf16* __restrict__ Vt, const bf16* __restrict__ gate,
    const float* __restrict__ ow, bf16* __restrict__ out) {
    const int T = 2048;
    __shared__ __align__(16) bf16 KsB[2][64 * 128];
    __shared__ __align__(16) bf16 VsB[2][128 * 64];
    int lane = threadIdx.x & 63, wave = threadIdx.x >> 6;
    int g = lane >> 4, c = lane & 15;
    int wg = blockIdx.x;
    int bh = wg & 31;          // XCD = wg%8 = bh%8 -> 4 heads per XCD (K+V = 4MB = one L2)
    int qt = 31 - (wg >> 5);   // heavy q-tiles launch first
    int q0 = qt * 64;
    const bf16* Qb = Q + (size_t)bh * T * 128;
    const bf16* Kb = K + (size_t)bh * T * 128;
    const bf16* Vb = Vt + (size_t)bh * 128 * T;

    int qrow = q0 + wave * 16 + c;
    bf16x8 qf[4];
#pragma unroll
    for (int kk = 0; kk < 4; kk++)
        qf[kk] = *reinterpret_cast<const bf16x8*>(&Qb[(size_t)qrow * 128 + kk * 32 + g * 8]);

    // staging constants: 4 waves x 4 chunks each for K and V; K rows permuted
    int kprow[4], klu[4], vrow[4], vlu[4];
#pragma unroll
    for (int i = 0; i < 4; i++) {
        int ch = wave * 4 + i;
        int p = ch * 4 + (lane >> 4);                       // staged K row position 0..63
        kprow[i] = ((p >> 5) & 1) * 32 + ((p >> 2) & 3) * 8 + ((p >> 4) & 1) * 4 + (p & 3);
        klu[i] = (lane & 15) ^ (p & 7);
        vrow[i] = ch * 8 + (lane >> 3);                     // V d-row 0..127 (linear)
        vlu[i] = (lane & 7) ^ (vrow[i] & 7);
    }
    auto stage = [&](int kv0, int b) {
#pragma unroll
        for (int i = 0; i < 4; i++) {
            int ch = wave * 4 + i;
            gload16(&Kb[(size_t)(kv0 + kprow[i]) * 128 + klu[i] * 8], &KsB[b][ch * 512]);
            gload16(&Vb[(size_t)vrow[i] * T + kv0 + vlu[i] * 8], &VsB[b][ch * 512]);
        }
    };

    f32x4 acc[8];
#pragma unroll
    for (int i = 0; i < 8; i++) acc[i] = {0.f, 0.f, 0.f, 0.f};
    float m = -INFINITY, l = 0.f;

    int ntiles = qt + 1;
    stage(0, 0);
    __syncthreads();
    int cur = 0;
    for (int it = 0; it < ntiles; ++it) {
        int kv0 = it * 64;
        if (it + 1 < ntiles) stage(kv0 + 64, cur ^ 1);
        const bf16* Ks = KsB[cur];
        const bf16* Vs = VsB[cur];

        f32x4 s[4];
#pragma unroll
        for (int nf = 0; nf < 4; nf++) s[nf] = {0.f, 0.f, 0.f, 0.f};
#pragma unroll
        for (int nf = 0; nf < 4; nf++)
#pragma unroll
            for (int kk = 0; kk < 4; kk++) {
                int pu = (kk * 4 + g) ^ (c & 7);
                bf16x8 kf = *reinterpret_cast<const bf16x8*>(&Ks[(nf * 16 + c) * 128 + pu * 8]);
                s[nf] = __builtin_amdgcn_mfma_f32_16x16x32_bf16(kf, qf[kk], s[nf], 0, 0, 0);
            }
        // causal mask on the permuted true kv: kv_true = kv0 + 32*(nf>>1) + 8g + 4*(nf&1) + r
        if (it == ntiles - 1) {
#pragma unroll
            for (int nf = 0; nf < 4; nf++)
#pragma unroll
                for (int r = 0; r < 4; r++)
                    if (kv0 + (nf >> 1) * 32 + g * 8 + (nf & 1) * 4 + r > qrow)
                        s[nf][r] = -1e30f;
        }
        float mx = -INFINITY;
#pragma unroll
        for (int nf = 0; nf < 4; nf++)
#pragma unroll
            for (int r = 0; r < 4; r++) mx = fmaxf(mx, s[nf][r]);
        mx = fmaxf(mx, __shfl_xor(mx, 16, 64));
        mx = fmaxf(mx, __shfl_xor(mx, 32, 64));
        if (__all(mx - m <= 8.0f)) {  // T13 defer-max
            float rsum = 0.f;
#pragma unroll
            for (int nf = 0; nf < 4; nf++)
#pragma unroll
                for (int r = 0; r < 4; r++) {
                    float p = __expf(s[nf][r] - m);
                    s[nf][r] = p;
                    rsum += p;
                }
            rsum += __shfl_xor(rsum, 16, 64);
            rsum += __shfl_xor(rsum, 32, 64);
            l += rsum;
        } else {
            float mnew = fmaxf(m, mx);
            float alpha = __expf(m - mnew);
            m = mnew;
            float rsum = 0.f;
#pragma unroll
            for (int nf = 0; nf < 4; nf++)
#pragma unroll
                for (int r = 0; r < 4; r++) {
                    float p = __expf(s[nf][r] - mnew);
                    s[nf][r] = p;
                    rsum += p;
                }
            rsum += __shfl_xor(rsum, 16, 64);
            rsum += __shfl_xor(rsum, 32, 64);
            l = l * alpha + rsum;
            float al[4];
#pragma unroll
            for (int r = 0; r < 4; r++) al[r] = __shfl(alpha, g * 4 + r, 64);
#pragma unroll
            for (int nf = 0; nf < 8; nf++)
#pragma unroll
                for (int r = 0; r < 4; r++) acc[nf][r] *= al[r];
        }
        // PV: A-frag fully in-register (permuted-K QK^T layout)
#pragma unroll
        for (int kk2 = 0; kk2 < 2; kk2++) {
            union { bf16 h[8]; bf16x8 v; } pf;
#pragma unroll
            for (int r = 0; r < 4; r++) {
                pf.h[r] = __float2bfloat16(s[2 * kk2][r]);
                pf.h[4 + r] = __float2bfloat16(s[2 * kk2 + 1][r]);
            }
#pragma unroll
            for (int nf = 0; nf < 8; nf++) {
                int pu = (kk2 * 4 + g) ^ (c & 7);
                bf16x8 vf = *reinterpret_cast<const bf16x8*>(&Vs[(nf * 16 + c) * 64 + pu * 8]);
                acc[nf] = __builtin_amdgcn_mfma_f32_16x16x32_bf16(pf.v, vf, acc[nf], 0, 0, 0);
            }
        }
        __syncthreads();
        cur ^= 1;
    }
    // ---- fused epilogue: 1/l, o-norm, silu(gate) ----
    float inv = 1.0f / l;
    float iv[4];
#pragma unroll
    for (int r = 0; r < 4; r++) iv[r] = __shfl(inv, g * 4 + r, 64);
    int b_ = bh >> 4, h = bh & 15;
    float owv[8];
#pragma unroll
    for (int nf = 0; nf < 8; nf++) owv[nf] = ow[nf * 16 + c];
#pragma unroll
    for (int r = 0; r < 4; r++) {
        int row = q0 + wave * 16 + g * 4 + r;
        float y[8];
        float ss = 0.f;
#pragma unroll
        for (int nf = 0; nf < 8; nf++) {
            y[nf] = acc[nf][r] * iv[r];
            ss += y[nf] * y[nf];
        }
        ss += __shfl_xor(ss, 1, 64);
        ss += __shfl_xor(ss, 2, 64);
        ss += __shfl_xor(ss, 4, 64);
        ss += __shfl_xor(ss, 8, 64);
        float rs = rsqrtf(ss * (1.0f / 128.0f) + 1e-5f);
        size_t gi = ((size_t)(b_ * T + row)) * 2048 + h * 128;
#pragma unroll
        for (int nf = 0; nf < 8; nf++) {
            int col = nf * 16 + c;
            float gv = __bfloat162float(gate[gi + col]);
            gv = gv / (1.f + __expf(-gv));
            out[gi + col] = __float2bfloat16(y[nf] * rs * owv[nf] * gv);
        }
    }
}

extern "C" void kernel_launch(void* const* d_in, const int* in_sizes, int n_in,
                              void* d_out, int out_size, void* d_ws, size_t ws_size,
                              hipStream_t stream) {
    const float* x  = (const float*)d_in[0];
    const float* Wq = (const float*)d_in[1];
    const float* Wk = (const float*)d_in[2];
    const float* Wv = (const float*)d_in[3];
    const float* Wg = (const float*)d_in[4];
    const float* Wo = (const float*)d_in[5];
    const float* qw = (const float*)d_in[6];
    const float* kw = (const float*)d_in[7];
    const float* ow = (const float*)d_in[8];

    const size_t M = 4096, HID = 2048;
    char* w = (char*)d_ws;
    bf16*  xb    = (bf16*)(w);                     // @0          16,777,216 B
    bf16*  Wt    = (bf16*)(w + 16777216);          // @16M        41,943,040 B [5][2048][2048]
    bf16*  qkvg  = (bf16*)(w + 58720256);          // @56M        67,108,864 B [4][4096][2048] bf16
    bf16*  q_att = (bf16*)(w + 125829120);         //             16,777,216 B [32][2048][128]
    bf16*  k_att = (bf16*)(w + 142606336);         //             16,777,216 B
    bf16*  vt    = (bf16*)(w + 159383552);         //             16,777,216 B [32][128][2048]
    float* tbl   = (float*)(w + 176160768);        //              1,048,576 B [2048][128]
    bf16*  yg    = (bf16*)(w + 177209344);         //             16,777,216 B [B*T][2048]

    k_cvt_bf16<<<8192, 256, 0, stream>>>(x, xb, (int)(M * HID / 4));
    k_rope_tbl<<<512, 256, 0, stream>>>(tbl);
    k_wtrans<<<dim3(32, 32, 5), dim3(64, 4), 0, stream>>>(Wq, Wk, Wv, Wg, Wo, Wt);
    // fused Q/K/V/Gate projection (v2c: pre-QUAD barriers removed for inter-wave slip)
    k_gemm256<<<512, 512, 0, stream>>>(xb, Wt, qkvg, (int)M, 2048, 2048);
    // rope + rms for q and k in one launch, vectorized bf16x8 (+ fold 1/sqrt(D) into q)
    k_rope_rms<<<dim3(4096, 2), 256, 0, stream>>>(qkvg, qkvg + M * HID, qw, kw, tbl,
                                                  q_att, k_att);
    k_vtrans<<<dim3(32, 2, 32), dim3(64, 4), 0, stream>>>(qkvg + 2 * M * HID, vt);
    // attention (QBLK=64, permuted-K, in-register P) with fused o-norm + silu(gate) -> yg
    k_attn<<<1024, 256, 0, stream>>>(q_att, k_att, vt, qkvg + 3 * M * HID, ow, yg);
    // output projection (m97 128^2, fp32 out)
    k_gemm<<<dim3(32, 16, 1), 256, 0, stream>>>(yg, Wt + (size_t)4 * 2048 * 2048, (float*)d_out,
                                                (int)M, 2048, 2048);
}